// Round 10
// baseline (427.434 us; speedup 1.0000x reference)
//
#include <hip/hip_runtime.h>

#define N_NODES_C 50000
#define N_EDGES_C 800000
#define DIM 128
#define NCLS 40
#define SCAN_NB ((N_NODES_C + 255) / 256)      // 196
#define NBUK 32
#define BCAP 32768

typedef __attribute__((ext_vector_type(8))) short bf16x8;
typedef __attribute__((ext_vector_type(4))) float f32x4;

__device__ inline float bf2f(unsigned short u) {
    union { unsigned int i; float f; } c;
    c.i = ((unsigned int)u) << 16;
    return c.f;
}
__device__ inline unsigned short f2bf(float f) {
    union { float f; unsigned int i; } c;
    c.f = f;
    unsigned int x = c.i;
    x += 0x7fffu + ((x >> 16) & 1u);   // RNE
    return (unsigned short)(x >> 16);
}
__device__ inline void unp8(const uint4& g, float* f) {
    f[0] = __uint_as_float(g.x << 16); f[1] = __uint_as_float(g.x & 0xFFFF0000u);
    f[2] = __uint_as_float(g.y << 16); f[3] = __uint_as_float(g.y & 0xFFFF0000u);
    f[4] = __uint_as_float(g.z << 16); f[5] = __uint_as_float(g.z & 0xFFFF0000u);
    f[6] = __uint_as_float(g.w << 16); f[7] = __uint_as_float(g.w & 0xFFFF0000u);
}

// ---------------------------------------------------------------------------
// preprocessing: [0,64) W->bf16 ; [64,68) scales (+ gcount zero in block 64)
__global__ __launch_bounds__(256) void k_pre(const float* __restrict__ W0,
                                             const float* __restrict__ W1,
                                             const float* __restrict__ W2,
                                             const float* __restrict__ W3,
                                             unsigned short* __restrict__ Wb,
                                             float* __restrict__ scale_inv,
                                             int* __restrict__ gcount) {
    int b = blockIdx.x;
    if (b < 64) {
        int m = b >> 4;
        int idx = (b & 15) * 256 + threadIdx.x;
        const float* W = m == 0 ? W0 : m == 1 ? W1 : m == 2 ? W2 : W3;
        float4 v = reinterpret_cast<const float4*>(W)[idx];
        reinterpret_cast<ushort4*>(Wb + (size_t)m * DIM * DIM)[idx] =
            make_ushort4(f2bf(v.x), f2bf(v.y), f2bf(v.z), f2bf(v.w));
        return;
    }
    b -= 64;
    if (b == 0 && threadIdx.x < NBUK) gcount[threadIdx.x] = 0;
    const float* W = b == 0 ? W0 : b == 1 ? W1 : b == 2 ? W2 : W3;
    float s = 0.f;
    for (int i = threadIdx.x; i < DIM * DIM; i += 256) {
        float v = W[i];
        s += v * v;
    }
    #pragma unroll
    for (int off = 32; off >= 1; off >>= 1) s += __shfl_down(s, off);
    __shared__ float red[4];
    int lane = threadIdx.x & 63, wid = threadIdx.x >> 6;
    if (lane == 0) red[wid] = s;
    __syncthreads();
    if (threadIdx.x == 0) {
        float tot = red[0] + red[1] + red[2] + red[3];
        scale_inv[b] = 1.0f / sqrtf(tot);
    }
}

// ---------------------------------------------------------------------------
// multisplit edges into NBUK dst-range buckets; packed (dst<<16)|src.
__global__ __launch_bounds__(256) void k_bucket(const int* __restrict__ A,
                                                int* __restrict__ gcount,
                                                unsigned int* __restrict__ ebuk, int E) {
    __shared__ int cnt[NBUK];
    __shared__ int gbase[NBUK];
    int tid = threadIdx.x;
    if (tid < NBUK) cnt[tid] = 0;
    __syncthreads();
    int e0 = blockIdx.x * 1024;
    int s[4], d[4], b[4], r[4];
    #pragma unroll
    for (int j = 0; j < 4; ++j) {
        int e = e0 + j * 256 + tid;
        if (e < E) {
            s[j] = A[e];
            d[j] = A[E + e];
            b[j] = (int)(((unsigned long long)(unsigned)d[j] * NBUK) / N_NODES_C);
            r[j] = atomicAdd(&cnt[b[j]], 1);
        } else {
            b[j] = -1;
        }
    }
    __syncthreads();
    if (tid < NBUK) gbase[tid] = atomicAdd(&gcount[tid], cnt[tid]);
    __syncthreads();
    #pragma unroll
    for (int j = 0; j < 4; ++j) {
        if (b[j] >= 0) {
            int pos = gbase[b[j]] + r[j];
            if (pos < BCAP)
                ebuk[(size_t)b[j] * BCAP + pos] =
                    ((unsigned)d[j] << 16) | (unsigned)s[j];
        }
    }
}

// per-bucket degree histogram in LDS
__global__ __launch_bounds__(256) void k_degb(const unsigned int* __restrict__ ebuk,
                                              const int* __restrict__ gcount,
                                              int* __restrict__ deg) {
    int k = blockIdx.x;
    int base = (k * N_NODES_C + NBUK - 1) / NBUK;
    int next = ((k + 1) * N_NODES_C + NBUK - 1) / NBUK;
    int sz = next - base;
    __shared__ int dl[1568];
    for (int i = threadIdx.x; i < sz; i += 256) dl[i] = 0;
    __syncthreads();
    int count = gcount[k];
    if (count > BCAP) count = BCAP;
    for (int i = threadIdx.x; i < count; i += 256) {
        int d = (int)(ebuk[(size_t)k * BCAP + i] >> 16);
        atomicAdd(&dl[d - base], 1);
    }
    __syncthreads();
    for (int i = threadIdx.x; i < sz; i += 256) deg[base + i] = dl[i];
}

__global__ __launch_bounds__(256) void k_scan_part(const int* __restrict__ cnt,
                                                   int* __restrict__ partial,
                                                   float* __restrict__ dinv,
                                                   int* __restrict__ fill, int n) {
    int idx = blockIdx.x * 256 + threadIdx.x;
    int v = (idx < n) ? cnt[idx] : 0;
    if (idx < n) {
        dinv[idx] = rsqrtf((float)v + 1.0f);
        fill[idx] = 0;
    }
    int s = v;
    #pragma unroll
    for (int off = 32; off >= 1; off >>= 1) s += __shfl_down(s, off);
    __shared__ int red[4];
    int lane = threadIdx.x & 63, wid = threadIdx.x >> 6;
    if (lane == 0) red[wid] = s;
    __syncthreads();
    if (threadIdx.x == 0) partial[blockIdx.x] = red[0] + red[1] + red[2] + red[3];
}

__global__ __launch_bounds__(256) void k_scan_final(const int* __restrict__ cnt,
                                                    const int* __restrict__ partial,
                                                    int* __restrict__ ptr, int n, int nb) {
    int tid = threadIdx.x, bid = blockIdx.x;
    int lane = tid & 63, wid = tid >> 6;
    int pv = (tid < nb) ? partial[tid] : 0;
    int vb = (tid < bid) ? pv : 0;
    int s1 = vb, s2 = pv;
    #pragma unroll
    for (int off = 32; off >= 1; off >>= 1) {
        s1 += __shfl_down(s1, off);
        s2 += __shfl_down(s2, off);
    }
    __shared__ int r1[4], r2[4];
    if (lane == 0) { r1[wid] = s1; r2[wid] = s2; }
    __syncthreads();
    __shared__ int sbase, stot;
    if (tid == 0) {
        sbase = r1[0] + r1[1] + r1[2] + r1[3];
        stot  = r2[0] + r2[1] + r2[2] + r2[3];
    }
    __syncthreads();
    int idx = bid * 256 + tid;
    int v = (idx < n) ? cnt[idx] : 0;
    int sc = v;
    #pragma unroll
    for (int off = 1; off < 64; off <<= 1) {
        int t = __shfl_up(sc, off);
        if (lane >= off) sc += t;
    }
    __shared__ int wsum[4], wpre[4];
    if (lane == 63) wsum[wid] = sc;
    __syncthreads();
    if (tid == 0) {
        int acc = 0;
        #pragma unroll
        for (int w = 0; w < 4; ++w) { wpre[w] = acc; acc += wsum[w]; }
    }
    __syncthreads();
    if (idx < n) ptr[idx] = sbase + wpre[wid] + sc - v;
    if (bid == 0 && tid == 0) ptr[n] = stot;
}

// fill phase: bucket k handled by blocks bid%NBUK==k -> XCD affinity
__global__ __launch_bounds__(256) void k_fillb(const unsigned int* __restrict__ ebuk,
                                               const int* __restrict__ gcount,
                                               const int* __restrict__ ptr,
                                               int* __restrict__ fill,
                                               unsigned short* __restrict__ esrc) {
    int k = blockIdx.x & (NBUK - 1);
    int c = blockIdx.x / NBUK;
    int count = gcount[k];
    if (count > BCAP) count = BCAP;
    int i0 = c * 1024;
    if (i0 >= count) return;
    #pragma unroll
    for (int j = 0; j < 4; ++j) {
        int i = i0 + j * 256 + threadIdx.x;
        if (i < count) {
            unsigned v = ebuk[(size_t)k * BCAP + i];
            int d = (int)(v >> 16);
            int s = (int)(v & 0xFFFFu);
            int pos = ptr[d] + atomicAdd(&fill[d], 1);
            esrc[pos] = (unsigned short)s;
        }
    }
}

// ---------------------------------------------------------------------------
// bf16 MFMA GEMM with dinv-prescale epilogue. F32A: A-operand is fp32 (layer 0)
template <bool F32A>
__global__ __launch_bounds__(256) void k_gemm_mfma(const void* __restrict__ Xp,
                                                   const unsigned short* __restrict__ Wb,
                                                   const float* __restrict__ scale_ptr,
                                                   const float* __restrict__ dinv,
                                                   unsigned short* __restrict__ Gb, int N) {
    int tid = threadIdx.x;
    int w = tid >> 6;
    int l = tid & 63;
    int l15 = l & 15;
    int lg = l >> 4;
    int arow = blockIdx.x * 64 + w * 16 + l15;
    if (arow >= N) arow = N - 1;
    float scale = scale_ptr[0];

    f32x4 acc[8];
    #pragma unroll
    for (int ct = 0; ct < 8; ++ct) acc[ct] = f32x4{0.f, 0.f, 0.f, 0.f};

    #pragma unroll
    for (int kc = 0; kc < 4; ++kc) {
        int ko = kc * 32 + lg * 8;
        bf16x8 a;
        if (F32A) {
            const float4* xf = reinterpret_cast<const float4*>(
                (const float*)Xp + (size_t)arow * DIM + ko);
            float4 u = xf[0], v = xf[1];
            a[0] = (short)f2bf(u.x); a[1] = (short)f2bf(u.y);
            a[2] = (short)f2bf(u.z); a[3] = (short)f2bf(u.w);
            a[4] = (short)f2bf(v.x); a[5] = (short)f2bf(v.y);
            a[6] = (short)f2bf(v.z); a[7] = (short)f2bf(v.w);
        } else {
            a = *reinterpret_cast<const bf16x8*>(
                (const unsigned short*)Xp + (size_t)arow * DIM + ko);
        }
        #pragma unroll
        for (int ct = 0; ct < 8; ++ct) {
            bf16x8 b = *reinterpret_cast<const bf16x8*>(&Wb[(size_t)(ct * 16 + l15) * DIM + ko]);
            acc[ct] = __builtin_amdgcn_mfma_f32_16x16x32_bf16(a, b, acc[ct], 0, 0, 0);
        }
    }
    int outrow0 = blockIdx.x * 64 + w * 16 + lg * 4;
    #pragma unroll
    for (int r = 0; r < 4; ++r) {
        int row = outrow0 + r;
        if (row < N) {
            float dv = dinv[row] * scale;
            #pragma unroll
            for (int ct = 0; ct < 8; ++ct)
                Gb[(size_t)row * DIM + ct * 16 + l15] = f2bf(acc[ct][r] * dv);
        }
    }
}

// ---------------------------------------------------------------------------
// aggregation: one node per WAVE, 4 nodes/block (grid exact: N%4==0 -> 12500).
// lane: grp=l>>4 (edge slot), li=l&15 (16B row chunk). 16-edge deep passes
// (4 uint4 in flight/lane). Butterfly leaves full sum in ALL lanes.
// MODE 0: first layer (no relu/skip); 1: mid (relu+skip); 2: last (+classifier)
template <int MODE>
__global__ __launch_bounds__(256) void k_agg(const unsigned short* __restrict__ Gb,
                                             const float* __restrict__ bias,
                                             const float* __restrict__ dinv,
                                             const int* __restrict__ ptr,
                                             const unsigned short* __restrict__ esrc,
                                             const unsigned short* __restrict__ skipb,
                                             unsigned short* __restrict__ outb,
                                             const float* __restrict__ Wf,
                                             const float* __restrict__ bf,
                                             float* __restrict__ outf) {
    __shared__ float hstage[4][DIM];   // used only by MODE 2
    int nloc = threadIdx.x >> 6;
    int n = blockIdx.x * 4 + nloc;
    int l = threadIdx.x & 63;
    int grp = l >> 4, li = l & 15;
    const uint4* __restrict__ Gv = reinterpret_cast<const uint4*>(Gb);
    int beg = ptr[n], end = ptr[n + 1];
    float acc[8] = {};
    float t[8];
    int e = beg;
    for (; e + 16 <= end; e += 16) {
        int s0 = esrc[e + grp];
        int s1 = esrc[e + 4 + grp];
        int s2 = esrc[e + 8 + grp];
        int s3 = esrc[e + 12 + grp];
        uint4 g0 = Gv[(size_t)s0 * 16 + li];
        uint4 g1 = Gv[(size_t)s1 * 16 + li];
        uint4 g2 = Gv[(size_t)s2 * 16 + li];
        uint4 g3 = Gv[(size_t)s3 * 16 + li];
        unp8(g0, t);
        #pragma unroll
        for (int j = 0; j < 8; ++j) acc[j] += t[j];
        unp8(g1, t);
        #pragma unroll
        for (int j = 0; j < 8; ++j) acc[j] += t[j];
        unp8(g2, t);
        #pragma unroll
        for (int j = 0; j < 8; ++j) acc[j] += t[j];
        unp8(g3, t);
        #pragma unroll
        for (int j = 0; j < 8; ++j) acc[j] += t[j];
    }
    for (; e + 4 <= end; e += 4) {
        int s0 = esrc[e + grp];
        uint4 g0 = Gv[(size_t)s0 * 16 + li];
        unp8(g0, t);
        #pragma unroll
        for (int j = 0; j < 8; ++j) acc[j] += t[j];
    }
    int rem = end - e;
    if (grp < rem) {
        int s0 = esrc[e + grp];
        uint4 g0 = Gv[(size_t)s0 * 16 + li];
        unp8(g0, t);
        #pragma unroll
        for (int j = 0; j < 8; ++j) acc[j] += t[j];
    }
    #pragma unroll
    for (int j = 0; j < 8; ++j) {
        acc[j] += __shfl_xor(acc[j], 16);
        acc[j] += __shfl_xor(acc[j], 32);
    }
    if (grp == 0) {
        float di = dinv[n];
        uint4 gu = Gv[(size_t)n * 16 + li];
        float gs[8];
        unp8(gu, gs);
        const float4* b4 = reinterpret_cast<const float4*>(bias);
        float4 ba = b4[li * 2], bb = b4[li * 2 + 1];
        float bv[8] = {ba.x, ba.y, ba.z, ba.w, bb.x, bb.y, bb.z, bb.w};
        float v[8];
        #pragma unroll
        for (int j = 0; j < 8; ++j) v[j] = fmaf(di, acc[j] + gs[j], bv[j]);
        if (MODE >= 1) {
            uint4 su = reinterpret_cast<const uint4*>(skipb)[(size_t)n * 16 + li];
            float ss[8];
            unp8(su, ss);
            #pragma unroll
            for (int j = 0; j < 8; ++j) v[j] = fmaxf(v[j], 0.f) + ss[j];
        }
        if (MODE == 2) {
            #pragma unroll
            for (int j = 0; j < 8; ++j) hstage[nloc][li * 8 + j] = v[j];
        } else {
            uint4 o;
            o.x = (unsigned)f2bf(v[0]) | ((unsigned)f2bf(v[1]) << 16);
            o.y = (unsigned)f2bf(v[2]) | ((unsigned)f2bf(v[3]) << 16);
            o.z = (unsigned)f2bf(v[4]) | ((unsigned)f2bf(v[5]) << 16);
            o.w = (unsigned)f2bf(v[6]) | ((unsigned)f2bf(v[7]) << 16);
            reinterpret_cast<uint4*>(outb)[(size_t)n * 16 + li] = o;
        }
    }
    if (MODE == 2) {
        __syncthreads();
        int tidx = threadIdx.x;
        if (tidx < 4 * NCLS) {
            int nl = tidx / NCLS;
            int o = tidx - nl * NCLS;
            const float4* wp = reinterpret_cast<const float4*>(&Wf[(size_t)o * DIM]);
            const float4* hp = reinterpret_cast<const float4*>(&hstage[nl][0]);
            float s = 0.f;
            #pragma unroll
            for (int k = 0; k < DIM / 4; ++k) {
                float4 wv = wp[k];
                float4 hv = hp[k];
                s += wv.x * hv.x + wv.y * hv.y + wv.z * hv.z + wv.w * hv.w;
            }
            outf[(size_t)(blockIdx.x * 4 + nl) * NCLS + o] = s + bf[o];
        }
    }
}

// ---------------------------------------------------------------------------
extern "C" void kernel_launch(void* const* d_in, const int* in_sizes, int n_in,
                              void* d_out, int out_size, void* d_ws, size_t ws_size,
                              hipStream_t stream) {
    (void)in_sizes; (void)n_in; (void)out_size; (void)ws_size;
    const float* X  = (const float*)d_in[0];
    const int*   A  = (const int*)d_in[1];
    const float* W0 = (const float*)d_in[2];
    const float* b0 = (const float*)d_in[3];
    const float* W1 = (const float*)d_in[4];
    const float* b1 = (const float*)d_in[5];
    const float* W2 = (const float*)d_in[6];
    const float* b2 = (const float*)d_in[7];
    const float* W3 = (const float*)d_in[8];
    const float* b3 = (const float*)d_in[9];
    const float* Wf = (const float*)d_in[10];
    const float* bf = (const float*)d_in[11];
    float* out = (float*)d_out;

    char* base_ws = (char*)d_ws;
    size_t off = 0;
    auto alloc = [&](size_t bytes) -> char* {
        char* p = base_ws + off;
        off = (off + bytes + 255) & ~(size_t)255;
        return p;
    };
    float* scale_inv = (float*)alloc(4 * sizeof(float));
    int*   deg    = (int*)alloc(N_NODES_C * sizeof(int));
    int*   fill   = (int*)alloc(N_NODES_C * sizeof(int));
    int*   ptr    = (int*)alloc((N_NODES_C + 1) * sizeof(int));
    float* dinv   = (float*)alloc(N_NODES_C * sizeof(float));
    int*   part   = (int*)alloc(SCAN_NB * sizeof(int));
    int*   gcount = (int*)alloc(NBUK * sizeof(int));
    unsigned int*   ebuk = (unsigned int*)alloc((size_t)NBUK * BCAP * sizeof(unsigned int));
    unsigned short* esrc = (unsigned short*)alloc((size_t)N_EDGES_C * sizeof(unsigned short));
    unsigned short* Gb  = (unsigned short*)alloc((size_t)N_NODES_C * DIM * sizeof(unsigned short));
    unsigned short* Hb1 = (unsigned short*)alloc((size_t)N_NODES_C * DIM * sizeof(unsigned short));
    unsigned short* Hb2 = (unsigned short*)alloc((size_t)N_NODES_C * DIM * sizeof(unsigned short));
    unsigned short* Wb  = (unsigned short*)alloc((size_t)4 * DIM * DIM * sizeof(unsigned short));

    k_pre<<<68, 256, 0, stream>>>(W0, W1, W2, W3, Wb, scale_inv, gcount);
    k_bucket<<<(N_EDGES_C + 1023) / 1024, 256, 0, stream>>>(A, gcount, ebuk, N_EDGES_C);
    k_degb<<<NBUK, 256, 0, stream>>>(ebuk, gcount, deg);
    k_scan_part<<<SCAN_NB, 256, 0, stream>>>(deg, part, dinv, fill, N_NODES_C);
    k_scan_final<<<SCAN_NB, 256, 0, stream>>>(deg, part, ptr, N_NODES_C, SCAN_NB);
    k_fillb<<<NBUK * (BCAP / 1024), 256, 0, stream>>>(ebuk, gcount, ptr, fill, esrc);

    const int gemm_grid = (N_NODES_C + 63) / 64;
    const int agg_grid  = N_NODES_C / 4;   // exact: 12500

    // layer 0 (A = fp32 X, converted in-register)
    k_gemm_mfma<true><<<gemm_grid, 256, 0, stream>>>(X, Wb + 0 * DIM * DIM, scale_inv + 0, dinv, Gb, N_NODES_C);
    k_agg<0><<<agg_grid, 256, 0, stream>>>(Gb, b0, dinv, ptr, esrc, nullptr, Hb1, nullptr, nullptr, nullptr);
    // layer 1
    k_gemm_mfma<false><<<gemm_grid, 256, 0, stream>>>(Hb1, Wb + 1 * DIM * DIM, scale_inv + 1, dinv, Gb, N_NODES_C);
    k_agg<1><<<agg_grid, 256, 0, stream>>>(Gb, b1, dinv, ptr, esrc, Hb1, Hb2, nullptr, nullptr, nullptr);
    // layer 2
    k_gemm_mfma<false><<<gemm_grid, 256, 0, stream>>>(Hb2, Wb + 2 * DIM * DIM, scale_inv + 2, dinv, Gb, N_NODES_C);
    k_agg<1><<<agg_grid, 256, 0, stream>>>(Gb, b2, dinv, ptr, esrc, Hb2, Hb1, nullptr, nullptr, nullptr);
    // layer 3 + fused classifier
    k_gemm_mfma<false><<<gemm_grid, 256, 0, stream>>>(Hb1, Wb + 3 * DIM * DIM, scale_inv + 3, dinv, Gb, N_NODES_C);
    k_agg<2><<<agg_grid, 256, 0, stream>>>(Gb, b3, dinv, ptr, esrc, Hb1, nullptr, Wf, bf, out);
}

// Round 11
// 340.107 us; speedup vs baseline: 1.2568x; 1.2568x over previous
//
#include <hip/hip_runtime.h>

#define N_NODES_C 50000
#define N_EDGES_C 800000
#define DIM 128
#define NCLS 40
#define SCAN_NB ((N_NODES_C + 255) / 256)      // 196
#define NBUK 32
#define BCAP 32768

typedef __attribute__((ext_vector_type(8))) short bf16x8;
typedef __attribute__((ext_vector_type(4))) float f32x4;

__device__ inline float bf2f(unsigned short u) {
    union { unsigned int i; float f; } c;
    c.i = ((unsigned int)u) << 16;
    return c.f;
}
__device__ inline unsigned short f2bf(float f) {
    union { float f; unsigned int i; } c;
    c.f = f;
    unsigned int x = c.i;
    x += 0x7fffu + ((x >> 16) & 1u);   // RNE
    return (unsigned short)(x >> 16);
}
__device__ inline void unp8(const uint4& g, float* f) {
    f[0] = __uint_as_float(g.x << 16); f[1] = __uint_as_float(g.x & 0xFFFF0000u);
    f[2] = __uint_as_float(g.y << 16); f[3] = __uint_as_float(g.y & 0xFFFF0000u);
    f[4] = __uint_as_float(g.z << 16); f[5] = __uint_as_float(g.z & 0xFFFF0000u);
    f[6] = __uint_as_float(g.w << 16); f[7] = __uint_as_float(g.w & 0xFFFF0000u);
}

// ---------------------------------------------------------------------------
// preprocessing: [0,64) W->bf16 ; [64,68) scales (+ gcount zero in block 64)
__global__ __launch_bounds__(256) void k_pre(const float* __restrict__ W0,
                                             const float* __restrict__ W1,
                                             const float* __restrict__ W2,
                                             const float* __restrict__ W3,
                                             unsigned short* __restrict__ Wb,
                                             float* __restrict__ scale_inv,
                                             int* __restrict__ gcount) {
    int b = blockIdx.x;
    if (b < 64) {
        int m = b >> 4;
        int idx = (b & 15) * 256 + threadIdx.x;
        const float* W = m == 0 ? W0 : m == 1 ? W1 : m == 2 ? W2 : W3;
        float4 v = reinterpret_cast<const float4*>(W)[idx];
        reinterpret_cast<ushort4*>(Wb + (size_t)m * DIM * DIM)[idx] =
            make_ushort4(f2bf(v.x), f2bf(v.y), f2bf(v.z), f2bf(v.w));
        return;
    }
    b -= 64;
    if (b == 0 && threadIdx.x < NBUK) gcount[threadIdx.x] = 0;
    const float* W = b == 0 ? W0 : b == 1 ? W1 : b == 2 ? W2 : W3;
    float s = 0.f;
    for (int i = threadIdx.x; i < DIM * DIM; i += 256) {
        float v = W[i];
        s += v * v;
    }
    #pragma unroll
    for (int off = 32; off >= 1; off >>= 1) s += __shfl_down(s, off);
    __shared__ float red[4];
    int lane = threadIdx.x & 63, wid = threadIdx.x >> 6;
    if (lane == 0) red[wid] = s;
    __syncthreads();
    if (threadIdx.x == 0) {
        float tot = red[0] + red[1] + red[2] + red[3];
        scale_inv[b] = 1.0f / sqrtf(tot);
    }
}

// ---------------------------------------------------------------------------
// multisplit edges into NBUK dst-range buckets; packed (dst<<16)|src.
__global__ __launch_bounds__(256) void k_bucket(const int* __restrict__ A,
                                                int* __restrict__ gcount,
                                                unsigned int* __restrict__ ebuk, int E) {
    __shared__ int cnt[NBUK];
    __shared__ int gbase[NBUK];
    int tid = threadIdx.x;
    if (tid < NBUK) cnt[tid] = 0;
    __syncthreads();
    int e0 = blockIdx.x * 1024;
    int s[4], d[4], b[4], r[4];
    #pragma unroll
    for (int j = 0; j < 4; ++j) {
        int e = e0 + j * 256 + tid;
        if (e < E) {
            s[j] = A[e];
            d[j] = A[E + e];
            b[j] = (int)(((unsigned long long)(unsigned)d[j] * NBUK) / N_NODES_C);
            r[j] = atomicAdd(&cnt[b[j]], 1);
        } else {
            b[j] = -1;
        }
    }
    __syncthreads();
    if (tid < NBUK) gbase[tid] = atomicAdd(&gcount[tid], cnt[tid]);
    __syncthreads();
    #pragma unroll
    for (int j = 0; j < 4; ++j) {
        if (b[j] >= 0) {
            int pos = gbase[b[j]] + r[j];
            if (pos < BCAP)
                ebuk[(size_t)b[j] * BCAP + pos] =
                    ((unsigned)d[j] << 16) | (unsigned)s[j];
        }
    }
}

// per-bucket degree histogram in LDS
__global__ __launch_bounds__(256) void k_degb(const unsigned int* __restrict__ ebuk,
                                              const int* __restrict__ gcount,
                                              int* __restrict__ deg) {
    int k = blockIdx.x;
    int base = (k * N_NODES_C + NBUK - 1) / NBUK;
    int next = ((k + 1) * N_NODES_C + NBUK - 1) / NBUK;
    int sz = next - base;
    __shared__ int dl[1568];
    for (int i = threadIdx.x; i < sz; i += 256) dl[i] = 0;
    __syncthreads();
    int count = gcount[k];
    if (count > BCAP) count = BCAP;
    for (int i = threadIdx.x; i < count; i += 256) {
        int d = (int)(ebuk[(size_t)k * BCAP + i] >> 16);
        atomicAdd(&dl[d - base], 1);
    }
    __syncthreads();
    for (int i = threadIdx.x; i < sz; i += 256) deg[base + i] = dl[i];
}

__global__ __launch_bounds__(256) void k_scan_part(const int* __restrict__ cnt,
                                                   int* __restrict__ partial,
                                                   float* __restrict__ dinv,
                                                   int* __restrict__ fill, int n) {
    int idx = blockIdx.x * 256 + threadIdx.x;
    int v = (idx < n) ? cnt[idx] : 0;
    if (idx < n) {
        dinv[idx] = rsqrtf((float)v + 1.0f);
        fill[idx] = 0;
    }
    int s = v;
    #pragma unroll
    for (int off = 32; off >= 1; off >>= 1) s += __shfl_down(s, off);
    __shared__ int red[4];
    int lane = threadIdx.x & 63, wid = threadIdx.x >> 6;
    if (lane == 0) red[wid] = s;
    __syncthreads();
    if (threadIdx.x == 0) partial[blockIdx.x] = red[0] + red[1] + red[2] + red[3];
}

__global__ __launch_bounds__(256) void k_scan_final(const int* __restrict__ cnt,
                                                    const int* __restrict__ partial,
                                                    int* __restrict__ ptr, int n, int nb) {
    int tid = threadIdx.x, bid = blockIdx.x;
    int lane = tid & 63, wid = tid >> 6;
    int pv = (tid < nb) ? partial[tid] : 0;
    int vb = (tid < bid) ? pv : 0;
    int s1 = vb, s2 = pv;
    #pragma unroll
    for (int off = 32; off >= 1; off >>= 1) {
        s1 += __shfl_down(s1, off);
        s2 += __shfl_down(s2, off);
    }
    __shared__ int r1[4], r2[4];
    if (lane == 0) { r1[wid] = s1; r2[wid] = s2; }
    __syncthreads();
    __shared__ int sbase, stot;
    if (tid == 0) {
        sbase = r1[0] + r1[1] + r1[2] + r1[3];
        stot  = r2[0] + r2[1] + r2[2] + r2[3];
    }
    __syncthreads();
    int idx = bid * 256 + tid;
    int v = (idx < n) ? cnt[idx] : 0;
    int sc = v;
    #pragma unroll
    for (int off = 1; off < 64; off <<= 1) {
        int t = __shfl_up(sc, off);
        if (lane >= off) sc += t;
    }
    __shared__ int wsum[4], wpre[4];
    if (lane == 63) wsum[wid] = sc;
    __syncthreads();
    if (tid == 0) {
        int acc = 0;
        #pragma unroll
        for (int w = 0; w < 4; ++w) { wpre[w] = acc; acc += wsum[w]; }
    }
    __syncthreads();
    if (idx < n) ptr[idx] = sbase + wpre[wid] + sc - v;
    if (bid == 0 && tid == 0) ptr[n] = stot;
}

// fill phase: bucket k handled by blocks bid%NBUK==k -> XCD affinity
__global__ __launch_bounds__(256) void k_fillb(const unsigned int* __restrict__ ebuk,
                                               const int* __restrict__ gcount,
                                               const int* __restrict__ ptr,
                                               int* __restrict__ fill,
                                               unsigned short* __restrict__ esrc) {
    int k = blockIdx.x & (NBUK - 1);
    int c = blockIdx.x / NBUK;
    int count = gcount[k];
    if (count > BCAP) count = BCAP;
    int i0 = c * 1024;
    if (i0 >= count) return;
    #pragma unroll
    for (int j = 0; j < 4; ++j) {
        int i = i0 + j * 256 + threadIdx.x;
        if (i < count) {
            unsigned v = ebuk[(size_t)k * BCAP + i];
            int d = (int)(v >> 16);
            int s = (int)(v & 0xFFFFu);
            int pos = ptr[d] + atomicAdd(&fill[d], 1);
            esrc[pos] = (unsigned short)s;
        }
    }
}

// ---------------------------------------------------------------------------
// bf16 MFMA GEMM with dinv-prescale epilogue. F32A: A-operand is fp32 (layer 0)
template <bool F32A>
__global__ __launch_bounds__(256) void k_gemm_mfma(const void* __restrict__ Xp,
                                                   const unsigned short* __restrict__ Wb,
                                                   const float* __restrict__ scale_ptr,
                                                   const float* __restrict__ dinv,
                                                   unsigned short* __restrict__ Gb, int N) {
    int tid = threadIdx.x;
    int w = tid >> 6;
    int l = tid & 63;
    int l15 = l & 15;
    int lg = l >> 4;
    int arow = blockIdx.x * 64 + w * 16 + l15;
    if (arow >= N) arow = N - 1;
    float scale = scale_ptr[0];

    f32x4 acc[8];
    #pragma unroll
    for (int ct = 0; ct < 8; ++ct) acc[ct] = f32x4{0.f, 0.f, 0.f, 0.f};

    #pragma unroll
    for (int kc = 0; kc < 4; ++kc) {
        int ko = kc * 32 + lg * 8;
        bf16x8 a;
        if (F32A) {
            const float4* xf = reinterpret_cast<const float4*>(
                (const float*)Xp + (size_t)arow * DIM + ko);
            float4 u = xf[0], v = xf[1];
            a[0] = (short)f2bf(u.x); a[1] = (short)f2bf(u.y);
            a[2] = (short)f2bf(u.z); a[3] = (short)f2bf(u.w);
            a[4] = (short)f2bf(v.x); a[5] = (short)f2bf(v.y);
            a[6] = (short)f2bf(v.z); a[7] = (short)f2bf(v.w);
        } else {
            a = *reinterpret_cast<const bf16x8*>(
                (const unsigned short*)Xp + (size_t)arow * DIM + ko);
        }
        #pragma unroll
        for (int ct = 0; ct < 8; ++ct) {
            bf16x8 b = *reinterpret_cast<const bf16x8*>(&Wb[(size_t)(ct * 16 + l15) * DIM + ko]);
            acc[ct] = __builtin_amdgcn_mfma_f32_16x16x32_bf16(a, b, acc[ct], 0, 0, 0);
        }
    }
    int outrow0 = blockIdx.x * 64 + w * 16 + lg * 4;
    #pragma unroll
    for (int r = 0; r < 4; ++r) {
        int row = outrow0 + r;
        if (row < N) {
            float dv = dinv[row] * scale;
            #pragma unroll
            for (int ct = 0; ct < 8; ++ct)
                Gb[(size_t)row * DIM + ct * 16 + l15] = f2bf(acc[ct][r] * dv);
        }
    }
}

// ---------------------------------------------------------------------------
// aggregation: one node per WAVE, 4 nodes/block, no LDS.
// lane: grp=l>>4 (edge slot), li=l&15 (16B row chunk).
// out = dinv[n]*(sum_edges G[src] + G[n]) + b  (+relu+skip), bf16 in/out.
template <bool RELU>
__global__ __launch_bounds__(256) void k_agg(const unsigned short* __restrict__ Gb,
                                             const float* __restrict__ bias,
                                             const float* __restrict__ dinv,
                                             const int* __restrict__ ptr,
                                             const unsigned short* __restrict__ esrc,
                                             const unsigned short* __restrict__ skipb,
                                             unsigned short* __restrict__ outb) {
    int n = blockIdx.x * 4 + (threadIdx.x >> 6);
    int l = threadIdx.x & 63;
    int grp = l >> 4, li = l & 15;
    const uint4* __restrict__ Gv = reinterpret_cast<const uint4*>(Gb);
    int beg = ptr[n], end = ptr[n + 1];
    float acc[8] = {};
    float t[8];
    int e = beg;
    for (; e + 16 <= end; e += 16) {
        int s0 = esrc[e + grp];
        int s1 = esrc[e + 4 + grp];
        int s2 = esrc[e + 8 + grp];
        int s3 = esrc[e + 12 + grp];
        uint4 g0 = Gv[(size_t)s0 * 16 + li];
        uint4 g1 = Gv[(size_t)s1 * 16 + li];
        uint4 g2 = Gv[(size_t)s2 * 16 + li];
        uint4 g3 = Gv[(size_t)s3 * 16 + li];
        unp8(g0, t);
        #pragma unroll
        for (int j = 0; j < 8; ++j) acc[j] += t[j];
        unp8(g1, t);
        #pragma unroll
        for (int j = 0; j < 8; ++j) acc[j] += t[j];
        unp8(g2, t);
        #pragma unroll
        for (int j = 0; j < 8; ++j) acc[j] += t[j];
        unp8(g3, t);
        #pragma unroll
        for (int j = 0; j < 8; ++j) acc[j] += t[j];
    }
    for (; e + 4 <= end; e += 4) {
        int s0 = esrc[e + grp];
        uint4 g0 = Gv[(size_t)s0 * 16 + li];
        unp8(g0, t);
        #pragma unroll
        for (int j = 0; j < 8; ++j) acc[j] += t[j];
    }
    int rem = end - e;
    if (grp < rem) {
        int s0 = esrc[e + grp];
        uint4 g0 = Gv[(size_t)s0 * 16 + li];
        unp8(g0, t);
        #pragma unroll
        for (int j = 0; j < 8; ++j) acc[j] += t[j];
    }
    #pragma unroll
    for (int j = 0; j < 8; ++j) {
        acc[j] += __shfl_xor(acc[j], 16);
        acc[j] += __shfl_xor(acc[j], 32);
    }
    if (grp == 0) {
        float di = dinv[n];
        uint4 gu = Gv[(size_t)n * 16 + li];
        float gs[8];
        unp8(gu, gs);
        const float4* b4 = reinterpret_cast<const float4*>(bias);
        float4 ba = b4[li * 2], bb = b4[li * 2 + 1];
        float bv[8] = {ba.x, ba.y, ba.z, ba.w, bb.x, bb.y, bb.z, bb.w};
        float v[8];
        #pragma unroll
        for (int j = 0; j < 8; ++j) v[j] = fmaf(di, acc[j] + gs[j], bv[j]);
        if (RELU) {
            uint4 su = reinterpret_cast<const uint4*>(skipb)[(size_t)n * 16 + li];
            float ss[8];
            unp8(su, ss);
            #pragma unroll
            for (int j = 0; j < 8; ++j) v[j] = fmaxf(v[j], 0.f) + ss[j];
        }
        uint4 o;
        o.x = (unsigned)f2bf(v[0]) | ((unsigned)f2bf(v[1]) << 16);
        o.y = (unsigned)f2bf(v[2]) | ((unsigned)f2bf(v[3]) << 16);
        o.z = (unsigned)f2bf(v[4]) | ((unsigned)f2bf(v[5]) << 16);
        o.w = (unsigned)f2bf(v[6]) | ((unsigned)f2bf(v[7]) << 16);
        reinterpret_cast<uint4*>(outb)[(size_t)n * 16 + li] = o;
    }
}

// ---------------------------------------------------------------------------
// final classifier, bf16 H input, fp32 Wf/compute/output (outs padded 40->64)
__global__ __launch_bounds__(256) void k_final(const unsigned short* __restrict__ Hb,
                                               const float* __restrict__ Wf,
                                               const float* __restrict__ bf,
                                               float* __restrict__ out, int N) {
    __shared__ float Xs[16][68];
    __shared__ float Ws[16][64];
    int tid = threadIdx.x;
    int n0 = blockIdx.x * 64;
    int tx = tid & 15;
    int ty = tid >> 4;
    float acc[4][4] = {};
    for (int k0 = 0; k0 < DIM; k0 += 16) {
        {
            int j = tid >> 2, kq = tid & 3;
            int row = n0 + j;
            if (row >= N) row = N - 1;
            ushort4 x4 = *reinterpret_cast<const ushort4*>(&Hb[(size_t)row * DIM + k0 + kq * 4]);
            Xs[kq * 4 + 0][j] = bf2f(x4.x);
            Xs[kq * 4 + 1][j] = bf2f(x4.y);
            Xs[kq * 4 + 2][j] = bf2f(x4.z);
            Xs[kq * 4 + 3][j] = bf2f(x4.w);
        }
        {
            int o = tid >> 2, kq = tid & 3;
            int om = o < NCLS ? o : o - NCLS;
            const float4 w4 = *reinterpret_cast<const float4*>(&Wf[(size_t)om * DIM + k0 + kq * 4]);
            Ws[kq * 4 + 0][o] = w4.x;
            Ws[kq * 4 + 1][o] = w4.y;
            Ws[kq * 4 + 2][o] = w4.z;
            Ws[kq * 4 + 3][o] = w4.w;
        }
        __syncthreads();
        #pragma unroll
        for (int k = 0; k < 16; ++k) {
            float4 w = *reinterpret_cast<const float4*>(&Ws[k][tx * 4]);
            float4 x = *reinterpret_cast<const float4*>(&Xs[k][ty * 4]);
            float xv[4] = {x.x, x.y, x.z, x.w};
            #pragma unroll
            for (int i = 0; i < 4; ++i) {
                acc[i][0] = fmaf(xv[i], w.x, acc[i][0]);
                acc[i][1] = fmaf(xv[i], w.y, acc[i][1]);
                acc[i][2] = fmaf(xv[i], w.z, acc[i][2]);
                acc[i][3] = fmaf(xv[i], w.w, acc[i][3]);
            }
        }
        __syncthreads();
    }
    if (tx >= 10) return;
    float4 b4 = make_float4(bf[tx * 4], bf[tx * 4 + 1], bf[tx * 4 + 2], bf[tx * 4 + 3]);
    #pragma unroll
    for (int i = 0; i < 4; ++i) {
        int row = n0 + ty * 4 + i;
        if (row < N) {
            float* op = &out[(size_t)row * NCLS + tx * 4];
            op[0] = acc[i][0] + b4.x;
            op[1] = acc[i][1] + b4.y;
            op[2] = acc[i][2] + b4.z;
            op[3] = acc[i][3] + b4.w;
        }
    }
}

// ---------------------------------------------------------------------------
extern "C" void kernel_launch(void* const* d_in, const int* in_sizes, int n_in,
                              void* d_out, int out_size, void* d_ws, size_t ws_size,
                              hipStream_t stream) {
    (void)in_sizes; (void)n_in; (void)out_size; (void)ws_size;
    const float* X  = (const float*)d_in[0];
    const int*   A  = (const int*)d_in[1];
    const float* W0 = (const float*)d_in[2];
    const float* b0 = (const float*)d_in[3];
    const float* W1 = (const float*)d_in[4];
    const float* b1 = (const float*)d_in[5];
    const float* W2 = (const float*)d_in[6];
    const float* b2 = (const float*)d_in[7];
    const float* W3 = (const float*)d_in[8];
    const float* b3 = (const float*)d_in[9];
    const float* Wf = (const float*)d_in[10];
    const float* bf = (const float*)d_in[11];
    float* out = (float*)d_out;

    char* base_ws = (char*)d_ws;
    size_t off = 0;
    auto alloc = [&](size_t bytes) -> char* {
        char* p = base_ws + off;
        off = (off + bytes + 255) & ~(size_t)255;
        return p;
    };
    float* scale_inv = (float*)alloc(4 * sizeof(float));
    int*   deg    = (int*)alloc(N_NODES_C * sizeof(int));
    int*   fill   = (int*)alloc(N_NODES_C * sizeof(int));
    int*   ptr    = (int*)alloc((N_NODES_C + 1) * sizeof(int));
    float* dinv   = (float*)alloc(N_NODES_C * sizeof(float));
    int*   part   = (int*)alloc(SCAN_NB * sizeof(int));
    int*   gcount = (int*)alloc(NBUK * sizeof(int));
    unsigned int*   ebuk = (unsigned int*)alloc((size_t)NBUK * BCAP * sizeof(unsigned int));
    unsigned short* esrc = (unsigned short*)alloc((size_t)N_EDGES_C * sizeof(unsigned short));
    unsigned short* Gb  = (unsigned short*)alloc((size_t)N_NODES_C * DIM * sizeof(unsigned short));
    unsigned short* Hb1 = (unsigned short*)alloc((size_t)N_NODES_C * DIM * sizeof(unsigned short));
    unsigned short* Hb2 = (unsigned short*)alloc((size_t)N_NODES_C * DIM * sizeof(unsigned short));
    unsigned short* Wb  = (unsigned short*)alloc((size_t)4 * DIM * DIM * sizeof(unsigned short));

    k_pre<<<68, 256, 0, stream>>>(W0, W1, W2, W3, Wb, scale_inv, gcount);
    k_bucket<<<(N_EDGES_C + 1023) / 1024, 256, 0, stream>>>(A, gcount, ebuk, N_EDGES_C);
    k_degb<<<NBUK, 256, 0, stream>>>(ebuk, gcount, deg);
    k_scan_part<<<SCAN_NB, 256, 0, stream>>>(deg, part, dinv, fill, N_NODES_C);
    k_scan_final<<<SCAN_NB, 256, 0, stream>>>(deg, part, ptr, N_NODES_C, SCAN_NB);
    k_fillb<<<NBUK * (BCAP / 1024), 256, 0, stream>>>(ebuk, gcount, ptr, fill, esrc);

    const int gemm_grid = (N_NODES_C + 63) / 64;
    const int agg_grid  = N_NODES_C / 4;   // exact: 12500

    // layer 0 (A = fp32 X, converted in-register)
    k_gemm_mfma<true><<<gemm_grid, 256, 0, stream>>>(X, Wb + 0 * DIM * DIM, scale_inv + 0, dinv, Gb, N_NODES_C);
    k_agg<false><<<agg_grid, 256, 0, stream>>>(Gb, b0, dinv, ptr, esrc, nullptr, Hb1);
    // layer 1
    k_gemm_mfma<false><<<gemm_grid, 256, 0, stream>>>(Hb1, Wb + 1 * DIM * DIM, scale_inv + 1, dinv, Gb, N_NODES_C);
    k_agg<true><<<agg_grid, 256, 0, stream>>>(Gb, b1, dinv, ptr, esrc, Hb1, Hb2);
    // layer 2
    k_gemm_mfma<false><<<gemm_grid, 256, 0, stream>>>(Hb2, Wb + 2 * DIM * DIM, scale_inv + 2, dinv, Gb, N_NODES_C);
    k_agg<true><<<agg_grid, 256, 0, stream>>>(Gb, b2, dinv, ptr, esrc, Hb2, Hb1);
    // layer 3
    k_gemm_mfma<false><<<gemm_grid, 256, 0, stream>>>(Hb1, Wb + 3 * DIM * DIM, scale_inv + 3, dinv, Gb, N_NODES_C);
    k_agg<true><<<agg_grid, 256, 0, stream>>>(Gb, b3, dinv, ptr, esrc, Hb1, Hb2);
    // final classifier
    k_final<<<(N_NODES_C + 63) / 64, 256, 0, stream>>>(Hb2, Wf, bf, out, N_NODES_C);
}

// Round 12
// 311.114 us; speedup vs baseline: 1.3739x; 1.0932x over previous
//
#include <hip/hip_runtime.h>

#define N_NODES_C 50000
#define N_EDGES_C 800000
#define DIM 128
#define NCLS 40
#define NBUK 32
#define BCAP 32768
#define NOCT 8

typedef __attribute__((ext_vector_type(8))) short bf16x8;
typedef __attribute__((ext_vector_type(4))) float f32x4;

__device__ inline float bf2f(unsigned short u) {
    union { unsigned int i; float f; } c;
    c.i = ((unsigned int)u) << 16;
    return c.f;
}
__device__ inline unsigned short f2bf(float f) {
    union { float f; unsigned int i; } c;
    c.f = f;
    unsigned int x = c.i;
    x += 0x7fffu + ((x >> 16) & 1u);   // RNE
    return (unsigned short)(x >> 16);
}
__device__ inline void unp8(const uint4& g, float* f) {
    f[0] = __uint_as_float(g.x << 16); f[1] = __uint_as_float(g.x & 0xFFFF0000u);
    f[2] = __uint_as_float(g.y << 16); f[3] = __uint_as_float(g.y & 0xFFFF0000u);
    f[4] = __uint_as_float(g.z << 16); f[5] = __uint_as_float(g.z & 0xFFFF0000u);
    f[6] = __uint_as_float(g.w << 16); f[7] = __uint_as_float(g.w & 0xFFFF0000u);
}

// ---------------------------------------------------------------------------
// preprocessing: [0,64) W->bf16 ; [64,68) scales (+ gcount zero in block 64)
__global__ __launch_bounds__(256) void k_pre(const float* __restrict__ W0,
                                             const float* __restrict__ W1,
                                             const float* __restrict__ W2,
                                             const float* __restrict__ W3,
                                             unsigned short* __restrict__ Wb,
                                             float* __restrict__ scale_inv,
                                             int* __restrict__ gcount) {
    int b = blockIdx.x;
    if (b < 64) {
        int m = b >> 4;
        int idx = (b & 15) * 256 + threadIdx.x;
        const float* W = m == 0 ? W0 : m == 1 ? W1 : m == 2 ? W2 : W3;
        float4 v = reinterpret_cast<const float4*>(W)[idx];
        reinterpret_cast<ushort4*>(Wb + (size_t)m * DIM * DIM)[idx] =
            make_ushort4(f2bf(v.x), f2bf(v.y), f2bf(v.z), f2bf(v.w));
        return;
    }
    b -= 64;
    if (b == 0 && threadIdx.x < NBUK) gcount[threadIdx.x] = 0;
    const float* W = b == 0 ? W0 : b == 1 ? W1 : b == 2 ? W2 : W3;
    float s = 0.f;
    for (int i = threadIdx.x; i < DIM * DIM; i += 256) {
        float v = W[i];
        s += v * v;
    }
    #pragma unroll
    for (int off = 32; off >= 1; off >>= 1) s += __shfl_down(s, off);
    __shared__ float red[4];
    int lane = threadIdx.x & 63, wid = threadIdx.x >> 6;
    if (lane == 0) red[wid] = s;
    __syncthreads();
    if (threadIdx.x == 0) {
        float tot = red[0] + red[1] + red[2] + red[3];
        scale_inv[b] = 1.0f / sqrtf(tot);
    }
}

// ---------------------------------------------------------------------------
// multisplit edges into NBUK dst-range buckets; packed (dst<<16)|src.
__global__ __launch_bounds__(256) void k_bucket(const int* __restrict__ A,
                                                int* __restrict__ gcount,
                                                unsigned int* __restrict__ ebuk, int E) {
    __shared__ int cnt[NBUK];
    __shared__ int gbase[NBUK];
    int tid = threadIdx.x;
    if (tid < NBUK) cnt[tid] = 0;
    __syncthreads();
    int e0 = blockIdx.x * 1024;
    int s[4], d[4], b[4], r[4];
    #pragma unroll
    for (int j = 0; j < 4; ++j) {
        int e = e0 + j * 256 + tid;
        if (e < E) {
            s[j] = A[e];
            d[j] = A[E + e];
            b[j] = (int)(((unsigned long long)(unsigned)d[j] * NBUK) / N_NODES_C);
            r[j] = atomicAdd(&cnt[b[j]], 1);
        } else {
            b[j] = -1;
        }
    }
    __syncthreads();
    if (tid < NBUK) gbase[tid] = atomicAdd(&gcount[tid], cnt[tid]);
    __syncthreads();
    #pragma unroll
    for (int j = 0; j < 4; ++j) {
        if (b[j] >= 0) {
            int pos = gbase[b[j]] + r[j];
            if (pos < BCAP)
                ebuk[(size_t)b[j] * BCAP + pos] =
                    ((unsigned)d[j] << 16) | (unsigned)s[j];
        }
    }
}

// ---------------------------------------------------------------------------
// fused CSR build: one block per dst-bucket.
// (dst,src-octant) histogram in LDS -> scan -> ptr/dinv -> ordered fill.
// esrc comes out grouped by src-octant per node => L2-friendly agg gathers.
__global__ __launch_bounds__(512) void k_csr(const unsigned int* __restrict__ ebuk,
                                             const int* __restrict__ gcount,
                                             int* __restrict__ ptr,
                                             float* __restrict__ dinv,
                                             unsigned short* __restrict__ esrc) {
    __shared__ int dlo[NOCT][1568];
    __shared__ int gc[NBUK];
    __shared__ int wsum2[8], wpre2[8];
    int k = blockIdx.x;
    int tid = threadIdx.x;
    int base = (k * N_NODES_C + NBUK - 1) / NBUK;
    int next = ((k + 1) * N_NODES_C + NBUK - 1) / NBUK;
    int sz = next - base;                      // <= 1563

    for (int i = tid; i < NOCT * 1568; i += 512) (&dlo[0][0])[i] = 0;
    if (tid < NBUK) gc[tid] = min(gcount[tid], BCAP);
    __syncthreads();

    int count = gc[k];
    int bucket_base = 0;
    #pragma unroll
    for (int j = 0; j < NBUK; ++j) bucket_base += (j < k) ? gc[j] : 0;
    const unsigned int* eb = ebuk + (size_t)k * BCAP;

    // pass 1: (dst, oct) histogram
    for (int i = tid; i < count; i += 512) {
        unsigned v = eb[i];
        int d = (int)(v >> 16) - base;
        int src = (int)(v & 0xFFFFu);
        int oct = (src * NOCT) / N_NODES_C;
        atomicAdd(&dlo[oct][d], 1);
    }
    __syncthreads();

    // per-thread chunk (4 nodes) sums, block scan, offsets
    int degloc[4];
    int mysum = 0;
    #pragma unroll
    for (int c = 0; c < 4; ++c) {
        int i = tid * 4 + c;
        int ds = 0;
        if (i < sz) {
            #pragma unroll
            for (int o = 0; o < NOCT; ++o) ds += dlo[o][i];
        }
        degloc[c] = ds;
        mysum += ds;
    }
    int lane = tid & 63, wid = tid >> 6;
    int sc = mysum;
    #pragma unroll
    for (int off = 1; off < 64; off <<= 1) {
        int t = __shfl_up(sc, off);
        if (lane >= off) sc += t;
    }
    if (lane == 63) wsum2[wid] = sc;
    __syncthreads();
    if (tid == 0) {
        int a = 0;
        #pragma unroll
        for (int w = 0; w < 8; ++w) { wpre2[w] = a; a += wsum2[w]; }
    }
    __syncthreads();
    int run = wpre2[wid] + sc - mysum;    // exclusive prefix of this thread's chunk
    #pragma unroll
    for (int c = 0; c < 4; ++c) {
        int i = tid * 4 + c;
        if (i < sz) {
            ptr[base + i] = bucket_base + run;
            dinv[base + i] = rsqrtf((float)degloc[c] + 1.0f);
            int r = run;
            #pragma unroll
            for (int o = 0; o < NOCT; ++o) {
                int t = dlo[o][i];
                dlo[o][i] = r;
                r += t;
            }
            run += degloc[c];
        }
    }
    if (k == NBUK - 1 && tid == 511) ptr[N_NODES_C] = bucket_base + run;
    __syncthreads();

    // pass 2: fill — slot from (dst,oct) offset => octant-grouped lists
    for (int i = tid; i < count; i += 512) {
        unsigned v = eb[i];
        int d = (int)(v >> 16) - base;
        int src = (int)(v & 0xFFFFu);
        int oct = (src * NOCT) / N_NODES_C;
        int pos = atomicAdd(&dlo[oct][d], 1);
        esrc[bucket_base + pos] = (unsigned short)src;
    }
}

// ---------------------------------------------------------------------------
// bf16 MFMA GEMM with dinv-prescale epilogue. F32A: A-operand is fp32 (layer 0)
template <bool F32A>
__global__ __launch_bounds__(256) void k_gemm_mfma(const void* __restrict__ Xp,
                                                   const unsigned short* __restrict__ Wb,
                                                   const float* __restrict__ scale_ptr,
                                                   const float* __restrict__ dinv,
                                                   unsigned short* __restrict__ Gb, int N) {
    int tid = threadIdx.x;
    int w = tid >> 6;
    int l = tid & 63;
    int l15 = l & 15;
    int lg = l >> 4;
    int arow = blockIdx.x * 64 + w * 16 + l15;
    if (arow >= N) arow = N - 1;
    float scale = scale_ptr[0];

    f32x4 acc[8];
    #pragma unroll
    for (int ct = 0; ct < 8; ++ct) acc[ct] = f32x4{0.f, 0.f, 0.f, 0.f};

    #pragma unroll
    for (int kc = 0; kc < 4; ++kc) {
        int ko = kc * 32 + lg * 8;
        bf16x8 a;
        if (F32A) {
            const float4* xf = reinterpret_cast<const float4*>(
                (const float*)Xp + (size_t)arow * DIM + ko);
            float4 u = xf[0], v = xf[1];
            a[0] = (short)f2bf(u.x); a[1] = (short)f2bf(u.y);
            a[2] = (short)f2bf(u.z); a[3] = (short)f2bf(u.w);
            a[4] = (short)f2bf(v.x); a[5] = (short)f2bf(v.y);
            a[6] = (short)f2bf(v.z); a[7] = (short)f2bf(v.w);
        } else {
            a = *reinterpret_cast<const bf16x8*>(
                (const unsigned short*)Xp + (size_t)arow * DIM + ko);
        }
        #pragma unroll
        for (int ct = 0; ct < 8; ++ct) {
            bf16x8 b = *reinterpret_cast<const bf16x8*>(&Wb[(size_t)(ct * 16 + l15) * DIM + ko]);
            acc[ct] = __builtin_amdgcn_mfma_f32_16x16x32_bf16(a, b, acc[ct], 0, 0, 0);
        }
    }
    int outrow0 = blockIdx.x * 64 + w * 16 + lg * 4;
    #pragma unroll
    for (int r = 0; r < 4; ++r) {
        int row = outrow0 + r;
        if (row < N) {
            float dv = dinv[row] * scale;
            #pragma unroll
            for (int ct = 0; ct < 8; ++ct)
                Gb[(size_t)row * DIM + ct * 16 + l15] = f2bf(acc[ct][r] * dv);
        }
    }
}

// ---------------------------------------------------------------------------
// aggregation: one node per WAVE, 4 nodes/block, no LDS.
// lane: grp=l>>4 (edge slot), li=l&15 (16B row chunk).
template <bool RELU>
__global__ __launch_bounds__(256) void k_agg(const unsigned short* __restrict__ Gb,
                                             const float* __restrict__ bias,
                                             const float* __restrict__ dinv,
                                             const int* __restrict__ ptr,
                                             const unsigned short* __restrict__ esrc,
                                             const unsigned short* __restrict__ skipb,
                                             unsigned short* __restrict__ outb) {
    int n = blockIdx.x * 4 + (threadIdx.x >> 6);
    int l = threadIdx.x & 63;
    int grp = l >> 4, li = l & 15;
    const uint4* __restrict__ Gv = reinterpret_cast<const uint4*>(Gb);
    int beg = ptr[n], end = ptr[n + 1];
    float acc[8] = {};
    float t[8];
    int e = beg;
    for (; e + 16 <= end; e += 16) {
        int s0 = esrc[e + grp];
        int s1 = esrc[e + 4 + grp];
        int s2 = esrc[e + 8 + grp];
        int s3 = esrc[e + 12 + grp];
        uint4 g0 = Gv[(size_t)s0 * 16 + li];
        uint4 g1 = Gv[(size_t)s1 * 16 + li];
        uint4 g2 = Gv[(size_t)s2 * 16 + li];
        uint4 g3 = Gv[(size_t)s3 * 16 + li];
        unp8(g0, t);
        #pragma unroll
        for (int j = 0; j < 8; ++j) acc[j] += t[j];
        unp8(g1, t);
        #pragma unroll
        for (int j = 0; j < 8; ++j) acc[j] += t[j];
        unp8(g2, t);
        #pragma unroll
        for (int j = 0; j < 8; ++j) acc[j] += t[j];
        unp8(g3, t);
        #pragma unroll
        for (int j = 0; j < 8; ++j) acc[j] += t[j];
    }
    for (; e + 4 <= end; e += 4) {
        int s0 = esrc[e + grp];
        uint4 g0 = Gv[(size_t)s0 * 16 + li];
        unp8(g0, t);
        #pragma unroll
        for (int j = 0; j < 8; ++j) acc[j] += t[j];
    }
    int rem = end - e;
    if (grp < rem) {
        int s0 = esrc[e + grp];
        uint4 g0 = Gv[(size_t)s0 * 16 + li];
        unp8(g0, t);
        #pragma unroll
        for (int j = 0; j < 8; ++j) acc[j] += t[j];
    }
    #pragma unroll
    for (int j = 0; j < 8; ++j) {
        acc[j] += __shfl_xor(acc[j], 16);
        acc[j] += __shfl_xor(acc[j], 32);
    }
    if (grp == 0) {
        float di = dinv[n];
        uint4 gu = Gv[(size_t)n * 16 + li];
        float gs[8];
        unp8(gu, gs);
        const float4* b4 = reinterpret_cast<const float4*>(bias);
        float4 ba = b4[li * 2], bb = b4[li * 2 + 1];
        float bv[8] = {ba.x, ba.y, ba.z, ba.w, bb.x, bb.y, bb.z, bb.w};
        float v[8];
        #pragma unroll
        for (int j = 0; j < 8; ++j) v[j] = fmaf(di, acc[j] + gs[j], bv[j]);
        if (RELU) {
            uint4 su = reinterpret_cast<const uint4*>(skipb)[(size_t)n * 16 + li];
            float ss[8];
            unp8(su, ss);
            #pragma unroll
            for (int j = 0; j < 8; ++j) v[j] = fmaxf(v[j], 0.f) + ss[j];
        }
        uint4 o;
        o.x = (unsigned)f2bf(v[0]) | ((unsigned)f2bf(v[1]) << 16);
        o.y = (unsigned)f2bf(v[2]) | ((unsigned)f2bf(v[3]) << 16);
        o.z = (unsigned)f2bf(v[4]) | ((unsigned)f2bf(v[5]) << 16);
        o.w = (unsigned)f2bf(v[6]) | ((unsigned)f2bf(v[7]) << 16);
        reinterpret_cast<uint4*>(outb)[(size_t)n * 16 + li] = o;
    }
}

// ---------------------------------------------------------------------------
// final classifier, bf16 H input, fp32 Wf/compute/output (outs padded 40->64)
__global__ __launch_bounds__(256) void k_final(const unsigned short* __restrict__ Hb,
                                               const float* __restrict__ Wf,
                                               const float* __restrict__ bf,
                                               float* __restrict__ out, int N) {
    __shared__ float Xs[16][68];
    __shared__ float Ws[16][64];
    int tid = threadIdx.x;
    int n0 = blockIdx.x * 64;
    int tx = tid & 15;
    int ty = tid >> 4;
    float acc[4][4] = {};
    for (int k0 = 0; k0 < DIM; k0 += 16) {
        {
            int j = tid >> 2, kq = tid & 3;
            int row = n0 + j;
            if (row >= N) row = N - 1;
            ushort4 x4 = *reinterpret_cast<const ushort4*>(&Hb[(size_t)row * DIM + k0 + kq * 4]);
            Xs[kq * 4 + 0][j] = bf2f(x4.x);
            Xs[kq * 4 + 1][j] = bf2f(x4.y);
            Xs[kq * 4 + 2][j] = bf2f(x4.z);
            Xs[kq * 4 + 3][j] = bf2f(x4.w);
        }
        {
            int o = tid >> 2, kq = tid & 3;
            int om = o < NCLS ? o : o - NCLS;
            const float4 w4 = *reinterpret_cast<const float4*>(&Wf[(size_t)om * DIM + k0 + kq * 4]);
            Ws[kq * 4 + 0][o] = w4.x;
            Ws[kq * 4 + 1][o] = w4.y;
            Ws[kq * 4 + 2][o] = w4.z;
            Ws[kq * 4 + 3][o] = w4.w;
        }
        __syncthreads();
        #pragma unroll
        for (int k = 0; k < 16; ++k) {
            float4 w = *reinterpret_cast<const float4*>(&Ws[k][tx * 4]);
            float4 x = *reinterpret_cast<const float4*>(&Xs[k][ty * 4]);
            float xv[4] = {x.x, x.y, x.z, x.w};
            #pragma unroll
            for (int i = 0; i < 4; ++i) {
                acc[i][0] = fmaf(xv[i], w.x, acc[i][0]);
                acc[i][1] = fmaf(xv[i], w.y, acc[i][1]);
                acc[i][2] = fmaf(xv[i], w.z, acc[i][2]);
                acc[i][3] = fmaf(xv[i], w.w, acc[i][3]);
            }
        }
        __syncthreads();
    }
    if (tx >= 10) return;
    float4 b4 = make_float4(bf[tx * 4], bf[tx * 4 + 1], bf[tx * 4 + 2], bf[tx * 4 + 3]);
    #pragma unroll
    for (int i = 0; i < 4; ++i) {
        int row = n0 + ty * 4 + i;
        if (row < N) {
            float* op = &out[(size_t)row * NCLS + tx * 4];
            op[0] = acc[i][0] + b4.x;
            op[1] = acc[i][1] + b4.y;
            op[2] = acc[i][2] + b4.z;
            op[3] = acc[i][3] + b4.w;
        }
    }
}

// ---------------------------------------------------------------------------
extern "C" void kernel_launch(void* const* d_in, const int* in_sizes, int n_in,
                              void* d_out, int out_size, void* d_ws, size_t ws_size,
                              hipStream_t stream) {
    (void)in_sizes; (void)n_in; (void)out_size; (void)ws_size;
    const float* X  = (const float*)d_in[0];
    const int*   A  = (const int*)d_in[1];
    const float* W0 = (const float*)d_in[2];
    const float* b0 = (const float*)d_in[3];
    const float* W1 = (const float*)d_in[4];
    const float* b1 = (const float*)d_in[5];
    const float* W2 = (const float*)d_in[6];
    const float* b2 = (const float*)d_in[7];
    const float* W3 = (const float*)d_in[8];
    const float* b3 = (const float*)d_in[9];
    const float* Wf = (const float*)d_in[10];
    const float* bf = (const float*)d_in[11];
    float* out = (float*)d_out;

    char* base_ws = (char*)d_ws;
    size_t off = 0;
    auto alloc = [&](size_t bytes) -> char* {
        char* p = base_ws + off;
        off = (off + bytes + 255) & ~(size_t)255;
        return p;
    };
    float* scale_inv = (float*)alloc(4 * sizeof(float));
    int*   ptr    = (int*)alloc((N_NODES_C + 1) * sizeof(int));
    float* dinv   = (float*)alloc(N_NODES_C * sizeof(float));
    int*   gcount = (int*)alloc(NBUK * sizeof(int));
    unsigned int*   ebuk = (unsigned int*)alloc((size_t)NBUK * BCAP * sizeof(unsigned int));
    unsigned short* esrc = (unsigned short*)alloc((size_t)N_EDGES_C * sizeof(unsigned short));
    unsigned short* Gb  = (unsigned short*)alloc((size_t)N_NODES_C * DIM * sizeof(unsigned short));
    unsigned short* Hb1 = (unsigned short*)alloc((size_t)N_NODES_C * DIM * sizeof(unsigned short));
    unsigned short* Hb2 = (unsigned short*)alloc((size_t)N_NODES_C * DIM * sizeof(unsigned short));
    unsigned short* Wb  = (unsigned short*)alloc((size_t)4 * DIM * DIM * sizeof(unsigned short));

    k_pre<<<68, 256, 0, stream>>>(W0, W1, W2, W3, Wb, scale_inv, gcount);
    k_bucket<<<(N_EDGES_C + 1023) / 1024, 256, 0, stream>>>(A, gcount, ebuk, N_EDGES_C);
    k_csr<<<NBUK, 512, 0, stream>>>(ebuk, gcount, ptr, dinv, esrc);

    const int gemm_grid = (N_NODES_C + 63) / 64;
    const int agg_grid  = N_NODES_C / 4;   // exact: 12500

    // layer 0 (A = fp32 X, converted in-register)
    k_gemm_mfma<true><<<gemm_grid, 256, 0, stream>>>(X, Wb + 0 * DIM * DIM, scale_inv + 0, dinv, Gb, N_NODES_C);
    k_agg<false><<<agg_grid, 256, 0, stream>>>(Gb, b0, dinv, ptr, esrc, nullptr, Hb1);
    // layer 1
    k_gemm_mfma<false><<<gemm_grid, 256, 0, stream>>>(Hb1, Wb + 1 * DIM * DIM, scale_inv + 1, dinv, Gb, N_NODES_C);
    k_agg<true><<<agg_grid, 256, 0, stream>>>(Gb, b1, dinv, ptr, esrc, Hb1, Hb2);
    // layer 2
    k_gemm_mfma<false><<<gemm_grid, 256, 0, stream>>>(Hb2, Wb + 2 * DIM * DIM, scale_inv + 2, dinv, Gb, N_NODES_C);
    k_agg<true><<<agg_grid, 256, 0, stream>>>(Gb, b2, dinv, ptr, esrc, Hb2, Hb1);
    // layer 3
    k_gemm_mfma<false><<<gemm_grid, 256, 0, stream>>>(Hb1, Wb + 3 * DIM * DIM, scale_inv + 3, dinv, Gb, N_NODES_C);
    k_agg<true><<<agg_grid, 256, 0, stream>>>(Gb, b3, dinv, ptr, esrc, Hb1, Hb2);
    // final classifier
    k_final<<<(N_NODES_C + 63) / 64, 256, 0, stream>>>(Hb2, Wf, bf, out, N_NODES_C);
}

// Round 13
// 299.105 us; speedup vs baseline: 1.4290x; 1.0401x over previous
//
#include <hip/hip_runtime.h>

#define N_NODES_C 50000
#define N_EDGES_C 800000
#define DIM 128
#define NCLS 40
#define NBUK 32
#define BCAP 32768
#define NOCT 16

typedef __attribute__((ext_vector_type(8))) short bf16x8;
typedef __attribute__((ext_vector_type(4))) float f32x4;

__device__ inline float bf2f(unsigned short u) {
    union { unsigned int i; float f; } c;
    c.i = ((unsigned int)u) << 16;
    return c.f;
}
__device__ inline unsigned short f2bf(float f) {
    union { float f; unsigned int i; } c;
    c.f = f;
    unsigned int x = c.i;
    x += 0x7fffu + ((x >> 16) & 1u);   // RNE
    return (unsigned short)(x >> 16);
}
__device__ inline void unp8(const uint4& g, float* f) {
    f[0] = __uint_as_float(g.x << 16); f[1] = __uint_as_float(g.x & 0xFFFF0000u);
    f[2] = __uint_as_float(g.y << 16); f[3] = __uint_as_float(g.y & 0xFFFF0000u);
    f[4] = __uint_as_float(g.z << 16); f[5] = __uint_as_float(g.z & 0xFFFF0000u);
    f[6] = __uint_as_float(g.w << 16); f[7] = __uint_as_float(g.w & 0xFFFF0000u);
}

// ---------------------------------------------------------------------------
// preprocessing: [0,64) W0..3->bf16 ; [64,69) Wf->bf16 ; [69,73) scales
__global__ __launch_bounds__(256) void k_pre(const float* __restrict__ W0,
                                             const float* __restrict__ W1,
                                             const float* __restrict__ W2,
                                             const float* __restrict__ W3,
                                             const float* __restrict__ Wf,
                                             unsigned short* __restrict__ Wb,
                                             unsigned short* __restrict__ Wfb,
                                             float* __restrict__ scale_inv,
                                             int* __restrict__ gcount) {
    int b = blockIdx.x;
    if (b < 64) {
        int m = b >> 4;
        int idx = (b & 15) * 256 + threadIdx.x;
        const float* W = m == 0 ? W0 : m == 1 ? W1 : m == 2 ? W2 : W3;
        float4 v = reinterpret_cast<const float4*>(W)[idx];
        reinterpret_cast<ushort4*>(Wb + (size_t)m * DIM * DIM)[idx] =
            make_ushort4(f2bf(v.x), f2bf(v.y), f2bf(v.z), f2bf(v.w));
        return;
    }
    b -= 64;
    if (b < 5) {   // Wf: 40*128 = 1280 float4s = 5 blocks
        int idx = b * 256 + threadIdx.x;
        float4 v = reinterpret_cast<const float4*>(Wf)[idx];
        reinterpret_cast<ushort4*>(Wfb)[idx] =
            make_ushort4(f2bf(v.x), f2bf(v.y), f2bf(v.z), f2bf(v.w));
        return;
    }
    b -= 5;
    if (b == 0 && threadIdx.x < NBUK) gcount[threadIdx.x] = 0;
    const float* W = b == 0 ? W0 : b == 1 ? W1 : b == 2 ? W2 : W3;
    float s = 0.f;
    for (int i = threadIdx.x; i < DIM * DIM; i += 256) {
        float v = W[i];
        s += v * v;
    }
    #pragma unroll
    for (int off = 32; off >= 1; off >>= 1) s += __shfl_down(s, off);
    __shared__ float red[4];
    int lane = threadIdx.x & 63, wid = threadIdx.x >> 6;
    if (lane == 0) red[wid] = s;
    __syncthreads();
    if (threadIdx.x == 0) {
        float tot = red[0] + red[1] + red[2] + red[3];
        scale_inv[b] = 1.0f / sqrtf(tot);
    }
}

// ---------------------------------------------------------------------------
// multisplit edges into NBUK dst-range buckets; packed (dst<<16)|src.
__global__ __launch_bounds__(256) void k_bucket(const int* __restrict__ A,
                                                int* __restrict__ gcount,
                                                unsigned int* __restrict__ ebuk, int E) {
    __shared__ int cnt[NBUK];
    __shared__ int gbase[NBUK];
    int tid = threadIdx.x;
    if (tid < NBUK) cnt[tid] = 0;
    __syncthreads();
    int e0 = blockIdx.x * 1024;
    int s[4], d[4], b[4], r[4];
    #pragma unroll
    for (int j = 0; j < 4; ++j) {
        int e = e0 + j * 256 + tid;
        if (e < E) {
            s[j] = A[e];
            d[j] = A[E + e];
            b[j] = (int)(((unsigned long long)(unsigned)d[j] * NBUK) / N_NODES_C);
            r[j] = atomicAdd(&cnt[b[j]], 1);
        } else {
            b[j] = -1;
        }
    }
    __syncthreads();
    if (tid < NBUK) gbase[tid] = atomicAdd(&gcount[tid], cnt[tid]);
    __syncthreads();
    #pragma unroll
    for (int j = 0; j < 4; ++j) {
        if (b[j] >= 0) {
            int pos = gbase[b[j]] + r[j];
            if (pos < BCAP)
                ebuk[(size_t)b[j] * BCAP + pos] =
                    ((unsigned)d[j] << 16) | (unsigned)s[j];
        }
    }
}

// ---------------------------------------------------------------------------
// fused CSR build: one block per dst-bucket. (dst, src-16th) histogram packed
// two-per-int in LDS -> scan -> ptr/dinv -> src-16th-ordered fill.
__global__ __launch_bounds__(512) void k_csr(const unsigned int* __restrict__ ebuk,
                                             const int* __restrict__ gcount,
                                             int* __restrict__ ptr,
                                             float* __restrict__ dinv,
                                             unsigned short* __restrict__ esrc) {
    __shared__ unsigned int dlo[NOCT / 2][1568];   // oct pairs packed u16|u16
    __shared__ int gc[NBUK];
    __shared__ int wsum2[8], wpre2[8];
    int k = blockIdx.x;
    int tid = threadIdx.x;
    int base = (k * N_NODES_C + NBUK - 1) / NBUK;
    int next = ((k + 1) * N_NODES_C + NBUK - 1) / NBUK;
    int sz = next - base;                      // <= 1563

    for (int i = tid; i < (NOCT / 2) * 1568; i += 512) (&dlo[0][0])[i] = 0;
    if (tid < NBUK) gc[tid] = min(gcount[tid], BCAP);
    __syncthreads();

    int count = gc[k];
    int bucket_base = 0;
    #pragma unroll
    for (int j = 0; j < NBUK; ++j) bucket_base += (j < k) ? gc[j] : 0;
    const unsigned int* eb = ebuk + (size_t)k * BCAP;

    // pass 1: (dst, oct) histogram, packed halves
    for (int i = tid; i < count; i += 512) {
        unsigned v = eb[i];
        int d = (int)(v >> 16) - base;
        int src = (int)(v & 0xFFFFu);
        int oct = (src * NOCT) / N_NODES_C;
        atomicAdd(&dlo[oct >> 1][d], 1u << ((oct & 1) * 16));
    }
    __syncthreads();

    // per-thread chunk (4 nodes) sums, block scan, offsets
    int degloc[4];
    int mysum = 0;
    #pragma unroll
    for (int c = 0; c < 4; ++c) {
        int i = tid * 4 + c;
        int ds = 0;
        if (i < sz) {
            #pragma unroll
            for (int p = 0; p < NOCT / 2; ++p) {
                unsigned v = dlo[p][i];
                ds += (int)(v & 0xFFFFu) + (int)(v >> 16);
            }
        }
        degloc[c] = ds;
        mysum += ds;
    }
    int lane = tid & 63, wid = tid >> 6;
    int sc = mysum;
    #pragma unroll
    for (int off = 1; off < 64; off <<= 1) {
        int t = __shfl_up(sc, off);
        if (lane >= off) sc += t;
    }
    if (lane == 63) wsum2[wid] = sc;
    __syncthreads();
    if (tid == 0) {
        int a = 0;
        #pragma unroll
        for (int w = 0; w < 8; ++w) { wpre2[w] = a; a += wsum2[w]; }
    }
    __syncthreads();
    int run = wpre2[wid] + sc - mysum;    // bucket-relative exclusive prefix
    #pragma unroll
    for (int c = 0; c < 4; ++c) {
        int i = tid * 4 + c;
        if (i < sz) {
            ptr[base + i] = bucket_base + run;
            dinv[base + i] = rsqrtf((float)degloc[c] + 1.0f);
            int r = run;
            #pragma unroll
            for (int p = 0; p < NOCT / 2; ++p) {
                unsigned v = dlo[p][i];
                int lo = (int)(v & 0xFFFFu), hi = (int)(v >> 16);
                dlo[p][i] = (unsigned)r | ((unsigned)(r + lo) << 16);
                r += lo + hi;
            }
            run += degloc[c];
        }
    }
    if (k == NBUK - 1 && tid == 511) ptr[N_NODES_C] = bucket_base + run;
    __syncthreads();

    // pass 2: fill — slot from (dst,oct) packed offset => octant-grouped lists
    for (int i = tid; i < count; i += 512) {
        unsigned v = eb[i];
        int d = (int)(v >> 16) - base;
        int src = (int)(v & 0xFFFFu);
        int oct = (src * NOCT) / N_NODES_C;
        unsigned old = atomicAdd(&dlo[oct >> 1][d], 1u << ((oct & 1) * 16));
        int pos = (int)((old >> ((oct & 1) * 16)) & 0xFFFFu);
        esrc[bucket_base + pos] = (unsigned short)src;
    }
}

// ---------------------------------------------------------------------------
// bf16 MFMA GEMM with dinv-prescale epilogue. F32A: A-operand is fp32 (layer 0)
template <bool F32A>
__global__ __launch_bounds__(256) void k_gemm_mfma(const void* __restrict__ Xp,
                                                   const unsigned short* __restrict__ Wb,
                                                   const float* __restrict__ scale_ptr,
                                                   const float* __restrict__ dinv,
                                                   unsigned short* __restrict__ Gb, int N) {
    int tid = threadIdx.x;
    int w = tid >> 6;
    int l = tid & 63;
    int l15 = l & 15;
    int lg = l >> 4;
    int arow = blockIdx.x * 64 + w * 16 + l15;
    if (arow >= N) arow = N - 1;
    float scale = scale_ptr[0];

    f32x4 acc[8];
    #pragma unroll
    for (int ct = 0; ct < 8; ++ct) acc[ct] = f32x4{0.f, 0.f, 0.f, 0.f};

    #pragma unroll
    for (int kc = 0; kc < 4; ++kc) {
        int ko = kc * 32 + lg * 8;
        bf16x8 a;
        if (F32A) {
            const float4* xf = reinterpret_cast<const float4*>(
                (const float*)Xp + (size_t)arow * DIM + ko);
            float4 u = xf[0], v = xf[1];
            a[0] = (short)f2bf(u.x); a[1] = (short)f2bf(u.y);
            a[2] = (short)f2bf(u.z); a[3] = (short)f2bf(u.w);
            a[4] = (short)f2bf(v.x); a[5] = (short)f2bf(v.y);
            a[6] = (short)f2bf(v.z); a[7] = (short)f2bf(v.w);
        } else {
            a = *reinterpret_cast<const bf16x8*>(
                (const unsigned short*)Xp + (size_t)arow * DIM + ko);
        }
        #pragma unroll
        for (int ct = 0; ct < 8; ++ct) {
            bf16x8 b = *reinterpret_cast<const bf16x8*>(&Wb[(size_t)(ct * 16 + l15) * DIM + ko]);
            acc[ct] = __builtin_amdgcn_mfma_f32_16x16x32_bf16(a, b, acc[ct], 0, 0, 0);
        }
    }
    int outrow0 = blockIdx.x * 64 + w * 16 + lg * 4;
    #pragma unroll
    for (int r = 0; r < 4; ++r) {
        int row = outrow0 + r;
        if (row < N) {
            float dv = dinv[row] * scale;
            #pragma unroll
            for (int ct = 0; ct < 8; ++ct)
                Gb[(size_t)row * DIM + ct * 16 + l15] = f2bf(acc[ct][r] * dv);
        }
    }
}

// ---------------------------------------------------------------------------
// aggregation: one node per WAVE, 4 nodes/block, no LDS. XCD-swizzled blocks.
// lane: grp=l>>4 (edge slot), li=l&15 (16B row chunk).
template <bool RELU>
__global__ __launch_bounds__(256) void k_agg(const unsigned short* __restrict__ Gb,
                                             const float* __restrict__ bias,
                                             const float* __restrict__ dinv,
                                             const int* __restrict__ ptr,
                                             const unsigned short* __restrict__ esrc,
                                             const unsigned short* __restrict__ skipb,
                                             unsigned short* __restrict__ outb) {
    // bijective XCD swizzle: nwg = 12500, q = 1562, r = 4
    int orig = blockIdx.x;
    int xcd = orig & 7;
    int idx = orig >> 3;
    int wgid = (xcd < 4 ? xcd * 1563 : 4 * 1563 + (xcd - 4) * 1562) + idx;

    int n = wgid * 4 + (threadIdx.x >> 6);
    int l = threadIdx.x & 63;
    int grp = l >> 4, li = l & 15;
    const uint4* __restrict__ Gv = reinterpret_cast<const uint4*>(Gb);
    int beg = ptr[n], end = ptr[n + 1];

    // hoisted epilogue loads: in flight under the gather loop
    uint4 gu = Gv[(size_t)n * 16 + li];
    uint4 su;
    if (RELU) su = reinterpret_cast<const uint4*>(skipb)[(size_t)n * 16 + li];
    const float4* b4p = reinterpret_cast<const float4*>(bias);
    float4 ba = b4p[li * 2], bb = b4p[li * 2 + 1];
    float di = dinv[n];

    float acc[8] = {};
    float t[8];
    int e = beg;
    for (; e + 16 <= end; e += 16) {
        int s0 = esrc[e + grp];
        int s1 = esrc[e + 4 + grp];
        int s2 = esrc[e + 8 + grp];
        int s3 = esrc[e + 12 + grp];
        uint4 g0 = Gv[(size_t)s0 * 16 + li];
        uint4 g1 = Gv[(size_t)s1 * 16 + li];
        uint4 g2 = Gv[(size_t)s2 * 16 + li];
        uint4 g3 = Gv[(size_t)s3 * 16 + li];
        unp8(g0, t);
        #pragma unroll
        for (int j = 0; j < 8; ++j) acc[j] += t[j];
        unp8(g1, t);
        #pragma unroll
        for (int j = 0; j < 8; ++j) acc[j] += t[j];
        unp8(g2, t);
        #pragma unroll
        for (int j = 0; j < 8; ++j) acc[j] += t[j];
        unp8(g3, t);
        #pragma unroll
        for (int j = 0; j < 8; ++j) acc[j] += t[j];
    }
    for (; e + 4 <= end; e += 4) {
        int s0 = esrc[e + grp];
        uint4 g0 = Gv[(size_t)s0 * 16 + li];
        unp8(g0, t);
        #pragma unroll
        for (int j = 0; j < 8; ++j) acc[j] += t[j];
    }
    int rem = end - e;
    if (grp < rem) {
        int s0 = esrc[e + grp];
        uint4 g0 = Gv[(size_t)s0 * 16 + li];
        unp8(g0, t);
        #pragma unroll
        for (int j = 0; j < 8; ++j) acc[j] += t[j];
    }
    #pragma unroll
    for (int j = 0; j < 8; ++j) {
        acc[j] += __shfl_xor(acc[j], 16);
        acc[j] += __shfl_xor(acc[j], 32);
    }
    if (grp == 0) {
        float gs[8];
        unp8(gu, gs);
        float bv[8] = {ba.x, ba.y, ba.z, ba.w, bb.x, bb.y, bb.z, bb.w};
        float v[8];
        #pragma unroll
        for (int j = 0; j < 8; ++j) v[j] = fmaf(di, acc[j] + gs[j], bv[j]);
        if (RELU) {
            float ss[8];
            unp8(su, ss);
            #pragma unroll
            for (int j = 0; j < 8; ++j) v[j] = fmaxf(v[j], 0.f) + ss[j];
        }
        uint4 o;
        o.x = (unsigned)f2bf(v[0]) | ((unsigned)f2bf(v[1]) << 16);
        o.y = (unsigned)f2bf(v[2]) | ((unsigned)f2bf(v[3]) << 16);
        o.z = (unsigned)f2bf(v[4]) | ((unsigned)f2bf(v[5]) << 16);
        o.w = (unsigned)f2bf(v[6]) | ((unsigned)f2bf(v[7]) << 16);
        reinterpret_cast<uint4*>(outb)[(size_t)n * 16 + li] = o;
    }
}

// ---------------------------------------------------------------------------
// final classifier via MFMA: out[n][o] = bf[o] + sum_k Hb[n][k]*Wfb[o][k]
// 64 rows/block (4 waves x 16); 3 col-tiles cover 40 outs (pad rows clamped).
__global__ __launch_bounds__(256) void k_final(const unsigned short* __restrict__ Hb,
                                               const unsigned short* __restrict__ Wfb,
                                               const float* __restrict__ bf,
                                               float* __restrict__ out, int N) {
    int tid = threadIdx.x;
    int w = tid >> 6;
    int l = tid & 63;
    int l15 = l & 15;
    int lg = l >> 4;
    int arow = blockIdx.x * 64 + w * 16 + l15;
    if (arow >= N) arow = N - 1;

    f32x4 acc[3];
    #pragma unroll
    for (int ct = 0; ct < 3; ++ct) acc[ct] = f32x4{0.f, 0.f, 0.f, 0.f};

    #pragma unroll
    for (int kc = 0; kc < 4; ++kc) {
        int ko = kc * 32 + lg * 8;
        bf16x8 a = *reinterpret_cast<const bf16x8*>(&Hb[(size_t)arow * DIM + ko]);
        #pragma unroll
        for (int ct = 0; ct < 3; ++ct) {
            int wr = ct * 16 + l15;
            if (wr >= NCLS) wr = 0;   // pad rows clamp (stores masked below)
            bf16x8 b = *reinterpret_cast<const bf16x8*>(&Wfb[(size_t)wr * DIM + ko]);
            acc[ct] = __builtin_amdgcn_mfma_f32_16x16x32_bf16(a, b, acc[ct], 0, 0, 0);
        }
    }
    int outrow0 = blockIdx.x * 64 + w * 16 + lg * 4;
    #pragma unroll
    for (int ct = 0; ct < 3; ++ct) {
        int c = ct * 16 + l15;
        if (c < NCLS) {
            float bias = bf[c];
            #pragma unroll
            for (int r = 0; r < 4; ++r) {
                int row = outrow0 + r;
                if (row < N) out[(size_t)row * NCLS + c] = acc[ct][r] + bias;
            }
        }
    }
}

// ---------------------------------------------------------------------------
extern "C" void kernel_launch(void* const* d_in, const int* in_sizes, int n_in,
                              void* d_out, int out_size, void* d_ws, size_t ws_size,
                              hipStream_t stream) {
    (void)in_sizes; (void)n_in; (void)out_size; (void)ws_size;
    const float* X  = (const float*)d_in[0];
    const int*   A  = (const int*)d_in[1];
    const float* W0 = (const float*)d_in[2];
    const float* b0 = (const float*)d_in[3];
    const float* W1 = (const float*)d_in[4];
    const float* b1 = (const float*)d_in[5];
    const float* W2 = (const float*)d_in[6];
    const float* b2 = (const float*)d_in[7];
    const float* W3 = (const float*)d_in[8];
    const float* b3 = (const float*)d_in[9];
    const float* Wf = (const float*)d_in[10];
    const float* bf = (const float*)d_in[11];
    float* out = (float*)d_out;

    char* base_ws = (char*)d_ws;
    size_t off = 0;
    auto alloc = [&](size_t bytes) -> char* {
        char* p = base_ws + off;
        off = (off + bytes + 255) & ~(size_t)255;
        return p;
    };
    float* scale_inv = (float*)alloc(4 * sizeof(float));
    int*   ptr    = (int*)alloc((N_NODES_C + 1) * sizeof(int));
    float* dinv   = (float*)alloc(N_NODES_C * sizeof(float));
    int*   gcount = (int*)alloc(NBUK * sizeof(int));
    unsigned int*   ebuk = (unsigned int*)alloc((size_t)NBUK * BCAP * sizeof(unsigned int));
    unsigned short* esrc = (unsigned short*)alloc((size_t)N_EDGES_C * sizeof(unsigned short));
    unsigned short* Gb  = (unsigned short*)alloc((size_t)N_NODES_C * DIM * sizeof(unsigned short));
    unsigned short* Hb1 = (unsigned short*)alloc((size_t)N_NODES_C * DIM * sizeof(unsigned short));
    unsigned short* Hb2 = (unsigned short*)alloc((size_t)N_NODES_C * DIM * sizeof(unsigned short));
    unsigned short* Wb  = (unsigned short*)alloc((size_t)4 * DIM * DIM * sizeof(unsigned short));
    unsigned short* Wfb = (unsigned short*)alloc((size_t)NCLS * DIM * sizeof(unsigned short));

    k_pre<<<73, 256, 0, stream>>>(W0, W1, W2, W3, Wf, Wb, Wfb, scale_inv, gcount);
    k_bucket<<<(N_EDGES_C + 1023) / 1024, 256, 0, stream>>>(A, gcount, ebuk, N_EDGES_C);
    k_csr<<<NBUK, 512, 0, stream>>>(ebuk, gcount, ptr, dinv, esrc);

    const int gemm_grid = (N_NODES_C + 63) / 64;
    const int agg_grid  = N_NODES_C / 4;   // exact: 12500

    // layer 0 (A = fp32 X, converted in-register)
    k_gemm_mfma<true><<<gemm_grid, 256, 0, stream>>>(X, Wb + 0 * DIM * DIM, scale_inv + 0, dinv, Gb, N_NODES_C);
    k_agg<false><<<agg_grid, 256, 0, stream>>>(Gb, b0, dinv, ptr, esrc, nullptr, Hb1);
    // layer 1
    k_gemm_mfma<false><<<gemm_grid, 256, 0, stream>>>(Hb1, Wb + 1 * DIM * DIM, scale_inv + 1, dinv, Gb, N_NODES_C);
    k_agg<true><<<agg_grid, 256, 0, stream>>>(Gb, b1, dinv, ptr, esrc, Hb1, Hb2);
    // layer 2
    k_gemm_mfma<false><<<gemm_grid, 256, 0, stream>>>(Hb2, Wb + 2 * DIM * DIM, scale_inv + 2, dinv, Gb, N_NODES_C);
    k_agg<true><<<agg_grid, 256, 0, stream>>>(Gb, b2, dinv, ptr, esrc, Hb2, Hb1);
    // layer 3
    k_gemm_mfma<false><<<gemm_grid, 256, 0, stream>>>(Hb1, Wb + 3 * DIM * DIM, scale_inv + 3, dinv, Gb, N_NODES_C);
    k_agg<true><<<agg_grid, 256, 0, stream>>>(Gb, b3, dinv, ptr, esrc, Hb1, Hb2);
    // final classifier (MFMA, bf16 Wf)
    k_final<<<(N_NODES_C + 63) / 64, 256, 0, stream>>>(Hb2, Wfb, bf, out, N_NODES_C);
}

// Round 14
// 293.384 us; speedup vs baseline: 1.4569x; 1.0195x over previous
//
#include <hip/hip_runtime.h>

#define N_NODES_C 50000
#define N_EDGES_C 800000
#define DIM 128
#define NCLS 40
#define NBUK 32
#define BCAP 32768
#define NOCT 16
#define SLAB 57344            // per-bucket esrc slab (padded worst case < 56k)
#define ZROW N_NODES_C        // all-zeros G row for pad edges

typedef __attribute__((ext_vector_type(8))) short bf16x8;
typedef __attribute__((ext_vector_type(4))) float f32x4;

__device__ inline float bf2f(unsigned short u) {
    union { unsigned int i; float f; } c;
    c.i = ((unsigned int)u) << 16;
    return c.f;
}
__device__ inline unsigned short f2bf(float f) {
    union { float f; unsigned int i; } c;
    c.f = f;
    unsigned int x = c.i;
    x += 0x7fffu + ((x >> 16) & 1u);   // RNE
    return (unsigned short)(x >> 16);
}
__device__ inline void unp8(const uint4& g, float* f) {
    f[0] = __uint_as_float(g.x << 16); f[1] = __uint_as_float(g.x & 0xFFFF0000u);
    f[2] = __uint_as_float(g.y << 16); f[3] = __uint_as_float(g.y & 0xFFFF0000u);
    f[4] = __uint_as_float(g.z << 16); f[5] = __uint_as_float(g.z & 0xFFFF0000u);
    f[6] = __uint_as_float(g.w << 16); f[7] = __uint_as_float(g.w & 0xFFFF0000u);
}

// ---------------------------------------------------------------------------
// preprocessing: [0,64) W0..3->bf16 ; [64,69) Wf->bf16 ; [69,73) scales ;
// block 73: zero Gb pad row (+ gcount zero in block 69)
__global__ __launch_bounds__(256) void k_pre(const float* __restrict__ W0,
                                             const float* __restrict__ W1,
                                             const float* __restrict__ W2,
                                             const float* __restrict__ W3,
                                             const float* __restrict__ Wf,
                                             unsigned short* __restrict__ Wb,
                                             unsigned short* __restrict__ Wfb,
                                             float* __restrict__ scale_inv,
                                             int* __restrict__ gcount,
                                             unsigned short* __restrict__ Gb) {
    int b = blockIdx.x;
    if (b < 64) {
        int m = b >> 4;
        int idx = (b & 15) * 256 + threadIdx.x;
        const float* W = m == 0 ? W0 : m == 1 ? W1 : m == 2 ? W2 : W3;
        float4 v = reinterpret_cast<const float4*>(W)[idx];
        reinterpret_cast<ushort4*>(Wb + (size_t)m * DIM * DIM)[idx] =
            make_ushort4(f2bf(v.x), f2bf(v.y), f2bf(v.z), f2bf(v.w));
        return;
    }
    b -= 64;
    if (b < 5) {   // Wf: 40*128 = 1280 float4s = 5 blocks
        int idx = b * 256 + threadIdx.x;
        float4 v = reinterpret_cast<const float4*>(Wf)[idx];
        reinterpret_cast<ushort4*>(Wfb)[idx] =
            make_ushort4(f2bf(v.x), f2bf(v.y), f2bf(v.z), f2bf(v.w));
        return;
    }
    b -= 5;
    if (b == 4) {  // zero the pad row of Gb
        if (threadIdx.x < DIM / 4)
            reinterpret_cast<ushort4*>(Gb + (size_t)ZROW * DIM)[threadIdx.x] =
                make_ushort4(0, 0, 0, 0);
        return;
    }
    if (b == 0 && threadIdx.x < NBUK) gcount[threadIdx.x] = 0;
    const float* W = b == 0 ? W0 : b == 1 ? W1 : b == 2 ? W2 : W3;
    float s = 0.f;
    for (int i = threadIdx.x; i < DIM * DIM; i += 256) {
        float v = W[i];
        s += v * v;
    }
    #pragma unroll
    for (int off = 32; off >= 1; off >>= 1) s += __shfl_down(s, off);
    __shared__ float red[4];
    int lane = threadIdx.x & 63, wid = threadIdx.x >> 6;
    if (lane == 0) red[wid] = s;
    __syncthreads();
    if (threadIdx.x == 0) {
        float tot = red[0] + red[1] + red[2] + red[3];
        scale_inv[b] = 1.0f / sqrtf(tot);
    }
}

// ---------------------------------------------------------------------------
// multisplit edges into NBUK dst-range buckets; packed (dst<<16)|src.
__global__ __launch_bounds__(256) void k_bucket(const int* __restrict__ A,
                                                int* __restrict__ gcount,
                                                unsigned int* __restrict__ ebuk, int E) {
    __shared__ int cnt[NBUK];
    __shared__ int gbase[NBUK];
    int tid = threadIdx.x;
    if (tid < NBUK) cnt[tid] = 0;
    __syncthreads();
    int e0 = blockIdx.x * 1024;
    int s[4], d[4], b[4], r[4];
    #pragma unroll
    for (int j = 0; j < 4; ++j) {
        int e = e0 + j * 256 + tid;
        if (e < E) {
            s[j] = A[e];
            d[j] = A[E + e];
            b[j] = (int)(((unsigned long long)(unsigned)d[j] * NBUK) / N_NODES_C);
            r[j] = atomicAdd(&cnt[b[j]], 1);
        } else {
            b[j] = -1;
        }
    }
    __syncthreads();
    if (tid < NBUK) gbase[tid] = atomicAdd(&gcount[tid], cnt[tid]);
    __syncthreads();
    #pragma unroll
    for (int j = 0; j < 4; ++j) {
        if (b[j] >= 0) {
            int pos = gbase[b[j]] + r[j];
            if (pos < BCAP)
                ebuk[(size_t)b[j] * BCAP + pos] =
                    ((unsigned)d[j] << 16) | (unsigned)s[j];
        }
    }
}

// ---------------------------------------------------------------------------
// fused CSR build, slab layout, 16-padded lists.
// ptr[n] = ((SLAB*k + run) << 8) | (degp/16); pads -> ZROW.
__global__ __launch_bounds__(512) void k_csr(const unsigned int* __restrict__ ebuk,
                                             const int* __restrict__ gcount,
                                             int* __restrict__ ptr,
                                             float* __restrict__ dinv,
                                             unsigned short* __restrict__ esrc) {
    __shared__ unsigned int dlo[NOCT / 2][1568];   // oct pairs packed u16|u16
    __shared__ int wsum2[8], wpre2[8];
    int k = blockIdx.x;
    int tid = threadIdx.x;
    int base = (k * N_NODES_C + NBUK - 1) / NBUK;
    int next = ((k + 1) * N_NODES_C + NBUK - 1) / NBUK;
    int sz = next - base;                      // <= 1563

    for (int i = tid; i < (NOCT / 2) * 1568; i += 512) (&dlo[0][0])[i] = 0;
    __syncthreads();

    int count = min(gcount[k], BCAP);
    int bucket_base = k * SLAB;
    const unsigned int* eb = ebuk + (size_t)k * BCAP;

    // pass 1: (dst, oct) histogram, packed halves
    for (int i = tid; i < count; i += 512) {
        unsigned v = eb[i];
        int d = (int)(v >> 16) - base;
        int src = (int)(v & 0xFFFFu);
        int oct = (src * NOCT) / N_NODES_C;
        atomicAdd(&dlo[oct >> 1][d], 1u << ((oct & 1) * 16));
    }
    __syncthreads();

    // per-thread chunk (4 nodes): true degree + padded degree, block scan
    int degloc[4], degp[4];
    int mysum = 0;
    #pragma unroll
    for (int c = 0; c < 4; ++c) {
        int i = tid * 4 + c;
        int ds = 0;
        if (i < sz) {
            #pragma unroll
            for (int p = 0; p < NOCT / 2; ++p) {
                unsigned v = dlo[p][i];
                ds += (int)(v & 0xFFFFu) + (int)(v >> 16);
            }
        }
        degloc[c] = ds;
        degp[c] = (i < sz) ? ((ds + 15) & ~15) : 0;
        mysum += degp[c];
    }
    int lane = tid & 63, wid = tid >> 6;
    int sc = mysum;
    #pragma unroll
    for (int off = 1; off < 64; off <<= 1) {
        int t = __shfl_up(sc, off);
        if (lane >= off) sc += t;
    }
    if (lane == 63) wsum2[wid] = sc;
    __syncthreads();
    if (tid == 0) {
        int a = 0;
        #pragma unroll
        for (int w = 0; w < 8; ++w) { wpre2[w] = a; a += wsum2[w]; }
    }
    __syncthreads();
    int run = wpre2[wid] + sc - mysum;    // bucket-relative padded prefix
    #pragma unroll
    for (int c = 0; c < 4; ++c) {
        int i = tid * 4 + c;
        if (i < sz) {
            ptr[base + i] = ((bucket_base + run) << 8) | (degp[c] >> 4);
            dinv[base + i] = rsqrtf((float)degloc[c] + 1.0f);
            int r = run;
            #pragma unroll
            for (int p = 0; p < NOCT / 2; ++p) {
                unsigned v = dlo[p][i];
                int lo = (int)(v & 0xFFFFu), hi = (int)(v >> 16);
                dlo[p][i] = (unsigned)r | ((unsigned)(r + lo) << 16);
                r += lo + hi;
            }
            for (int j = degloc[c]; j < degp[c]; ++j)
                esrc[bucket_base + run + j] = (unsigned short)ZROW;
            run += degp[c];
        }
    }
    __syncthreads();

    // pass 2: fill — slot from (dst,oct) packed offset => octant-grouped lists
    for (int i = tid; i < count; i += 512) {
        unsigned v = eb[i];
        int d = (int)(v >> 16) - base;
        int src = (int)(v & 0xFFFFu);
        int oct = (src * NOCT) / N_NODES_C;
        unsigned old = atomicAdd(&dlo[oct >> 1][d], 1u << ((oct & 1) * 16));
        int pos = (int)((old >> ((oct & 1) * 16)) & 0xFFFFu);
        esrc[bucket_base + pos] = (unsigned short)src;
    }
}

// ---------------------------------------------------------------------------
// bf16 MFMA GEMM with dinv-prescale epilogue. F32A: A-operand is fp32 (layer 0)
template <bool F32A>
__global__ __launch_bounds__(256) void k_gemm_mfma(const void* __restrict__ Xp,
                                                   const unsigned short* __restrict__ Wb,
                                                   const float* __restrict__ scale_ptr,
                                                   const float* __restrict__ dinv,
                                                   unsigned short* __restrict__ Gb, int N) {
    int tid = threadIdx.x;
    int w = tid >> 6;
    int l = tid & 63;
    int l15 = l & 15;
    int lg = l >> 4;
    int arow = blockIdx.x * 64 + w * 16 + l15;
    if (arow >= N) arow = N - 1;
    float scale = scale_ptr[0];

    f32x4 acc[8];
    #pragma unroll
    for (int ct = 0; ct < 8; ++ct) acc[ct] = f32x4{0.f, 0.f, 0.f, 0.f};

    #pragma unroll
    for (int kc = 0; kc < 4; ++kc) {
        int ko = kc * 32 + lg * 8;
        bf16x8 a;
        if (F32A) {
            const float4* xf = reinterpret_cast<const float4*>(
                (const float*)Xp + (size_t)arow * DIM + ko);
            float4 u = xf[0], v = xf[1];
            a[0] = (short)f2bf(u.x); a[1] = (short)f2bf(u.y);
            a[2] = (short)f2bf(u.z); a[3] = (short)f2bf(u.w);
            a[4] = (short)f2bf(v.x); a[5] = (short)f2bf(v.y);
            a[6] = (short)f2bf(v.z); a[7] = (short)f2bf(v.w);
        } else {
            a = *reinterpret_cast<const bf16x8*>(
                (const unsigned short*)Xp + (size_t)arow * DIM + ko);
        }
        #pragma unroll
        for (int ct = 0; ct < 8; ++ct) {
            bf16x8 b = *reinterpret_cast<const bf16x8*>(&Wb[(size_t)(ct * 16 + l15) * DIM + ko]);
            acc[ct] = __builtin_amdgcn_mfma_f32_16x16x32_bf16(a, b, acc[ct], 0, 0, 0);
        }
    }
    int outrow0 = blockIdx.x * 64 + w * 16 + lg * 4;
    #pragma unroll
    for (int r = 0; r < 4; ++r) {
        int row = outrow0 + r;
        if (row < N) {
            float dv = dinv[row] * scale;
            #pragma unroll
            for (int ct = 0; ct < 8; ++ct)
                Gb[(size_t)row * DIM + ct * 16 + l15] = f2bf(acc[ct][r] * dv);
        }
    }
}

// ---------------------------------------------------------------------------
// aggregation: one node per WAVE, 4 nodes/block, no LDS, XCD-swizzled.
// padded lists: exactly niter fully-parallel 16-edge passes, no tails.
template <bool RELU>
__global__ __launch_bounds__(256) void k_agg(const unsigned short* __restrict__ Gb,
                                             const float* __restrict__ bias,
                                             const float* __restrict__ dinv,
                                             const int* __restrict__ ptr,
                                             const unsigned short* __restrict__ esrc,
                                             const unsigned short* __restrict__ skipb,
                                             unsigned short* __restrict__ outb) {
    // bijective XCD swizzle: nwg = 12500, q = 1562, r = 4
    int orig = blockIdx.x;
    int xcd = orig & 7;
    int idx = orig >> 3;
    int wgid = (xcd < 4 ? xcd * 1563 : 4 * 1563 + (xcd - 4) * 1562) + idx;

    int n = wgid * 4 + (threadIdx.x >> 6);
    int l = threadIdx.x & 63;
    int grp = l >> 4, li = l & 15;
    const uint4* __restrict__ Gv = reinterpret_cast<const uint4*>(Gb);
    int p = ptr[n];
    int beg = p >> 8;
    int niter = p & 255;

    // hoisted epilogue loads: in flight under the gather loop
    uint4 gu = Gv[(size_t)n * 16 + li];
    uint4 su;
    if (RELU) su = reinterpret_cast<const uint4*>(skipb)[(size_t)n * 16 + li];
    const float4* b4p = reinterpret_cast<const float4*>(bias);
    float4 ba = b4p[li * 2], bb = b4p[li * 2 + 1];
    float di = dinv[n];

    float acc[8] = {};
    float t[8];
    for (int it = 0; it < niter; ++it) {
        int e = beg + it * 16;
        int s0 = esrc[e + grp];
        int s1 = esrc[e + 4 + grp];
        int s2 = esrc[e + 8 + grp];
        int s3 = esrc[e + 12 + grp];
        uint4 g0 = Gv[(size_t)s0 * 16 + li];
        uint4 g1 = Gv[(size_t)s1 * 16 + li];
        uint4 g2 = Gv[(size_t)s2 * 16 + li];
        uint4 g3 = Gv[(size_t)s3 * 16 + li];
        unp8(g0, t);
        #pragma unroll
        for (int j = 0; j < 8; ++j) acc[j] += t[j];
        unp8(g1, t);
        #pragma unroll
        for (int j = 0; j < 8; ++j) acc[j] += t[j];
        unp8(g2, t);
        #pragma unroll
        for (int j = 0; j < 8; ++j) acc[j] += t[j];
        unp8(g3, t);
        #pragma unroll
        for (int j = 0; j < 8; ++j) acc[j] += t[j];
    }
    #pragma unroll
    for (int j = 0; j < 8; ++j) {
        acc[j] += __shfl_xor(acc[j], 16);
        acc[j] += __shfl_xor(acc[j], 32);
    }
    if (grp == 0) {
        float gs[8];
        unp8(gu, gs);
        float bv[8] = {ba.x, ba.y, ba.z, ba.w, bb.x, bb.y, bb.z, bb.w};
        float v[8];
        #pragma unroll
        for (int j = 0; j < 8; ++j) v[j] = fmaf(di, acc[j] + gs[j], bv[j]);
        if (RELU) {
            float ss[8];
            unp8(su, ss);
            #pragma unroll
            for (int j = 0; j < 8; ++j) v[j] = fmaxf(v[j], 0.f) + ss[j];
        }
        uint4 o;
        o.x = (unsigned)f2bf(v[0]) | ((unsigned)f2bf(v[1]) << 16);
        o.y = (unsigned)f2bf(v[2]) | ((unsigned)f2bf(v[3]) << 16);
        o.z = (unsigned)f2bf(v[4]) | ((unsigned)f2bf(v[5]) << 16);
        o.w = (unsigned)f2bf(v[6]) | ((unsigned)f2bf(v[7]) << 16);
        reinterpret_cast<uint4*>(outb)[(size_t)n * 16 + li] = o;
    }
}

// ---------------------------------------------------------------------------
// final classifier via MFMA: out[n][o] = bf[o] + sum_k Hb[n][k]*Wfb[o][k]
__global__ __launch_bounds__(256) void k_final(const unsigned short* __restrict__ Hb,
                                               const unsigned short* __restrict__ Wfb,
                                               const float* __restrict__ bf,
                                               float* __restrict__ out, int N) {
    int tid = threadIdx.x;
    int w = tid >> 6;
    int l = tid & 63;
    int l15 = l & 15;
    int lg = l >> 4;
    int arow = blockIdx.x * 64 + w * 16 + l15;
    if (arow >= N) arow = N - 1;

    f32x4 acc[3];
    #pragma unroll
    for (int ct = 0; ct < 3; ++ct) acc[ct] = f32x4{0.f, 0.f, 0.f, 0.f};

    #pragma unroll
    for (int kc = 0; kc < 4; ++kc) {
        int ko = kc * 32 + lg * 8;
        bf16x8 a = *reinterpret_cast<const bf16x8*>(&Hb[(size_t)arow * DIM + ko]);
        #pragma unroll
        for (int ct = 0; ct < 3; ++ct) {
            int wr = ct * 16 + l15;
            if (wr >= NCLS) wr = 0;   // pad rows clamp (stores masked below)
            bf16x8 b = *reinterpret_cast<const bf16x8*>(&Wfb[(size_t)wr * DIM + ko]);
            acc[ct] = __builtin_amdgcn_mfma_f32_16x16x32_bf16(a, b, acc[ct], 0, 0, 0);
        }
    }
    int outrow0 = blockIdx.x * 64 + w * 16 + lg * 4;
    #pragma unroll
    for (int ct = 0; ct < 3; ++ct) {
        int c = ct * 16 + l15;
        if (c < NCLS) {
            float bias = bf[c];
            #pragma unroll
            for (int r = 0; r < 4; ++r) {
                int row = outrow0 + r;
                if (row < N) out[(size_t)row * NCLS + c] = acc[ct][r] + bias;
            }
        }
    }
}

// ---------------------------------------------------------------------------
extern "C" void kernel_launch(void* const* d_in, const int* in_sizes, int n_in,
                              void* d_out, int out_size, void* d_ws, size_t ws_size,
                              hipStream_t stream) {
    (void)in_sizes; (void)n_in; (void)out_size; (void)ws_size;
    const float* X  = (const float*)d_in[0];
    const int*   A  = (const int*)d_in[1];
    const float* W0 = (const float*)d_in[2];
    const float* b0 = (const float*)d_in[3];
    const float* W1 = (const float*)d_in[4];
    const float* b1 = (const float*)d_in[5];
    const float* W2 = (const float*)d_in[6];
    const float* b2 = (const float*)d_in[7];
    const float* W3 = (const float*)d_in[8];
    const float* b3 = (const float*)d_in[9];
    const float* Wf = (const float*)d_in[10];
    const float* bf = (const float*)d_in[11];
    float* out = (float*)d_out;

    char* base_ws = (char*)d_ws;
    size_t off = 0;
    auto alloc = [&](size_t bytes) -> char* {
        char* p = base_ws + off;
        off = (off + bytes + 255) & ~(size_t)255;
        return p;
    };
    float* scale_inv = (float*)alloc(4 * sizeof(float));
    int*   ptr    = (int*)alloc(N_NODES_C * sizeof(int));
    float* dinv   = (float*)alloc(N_NODES_C * sizeof(float));
    int*   gcount = (int*)alloc(NBUK * sizeof(int));
    unsigned int*   ebuk = (unsigned int*)alloc((size_t)NBUK * BCAP * sizeof(unsigned int));
    unsigned short* esrc = (unsigned short*)alloc((size_t)NBUK * SLAB * sizeof(unsigned short));
    unsigned short* Gb  = (unsigned short*)alloc((size_t)(N_NODES_C + 1) * DIM * sizeof(unsigned short));
    unsigned short* Hb1 = (unsigned short*)alloc((size_t)N_NODES_C * DIM * sizeof(unsigned short));
    unsigned short* Hb2 = (unsigned short*)alloc((size_t)N_NODES_C * DIM * sizeof(unsigned short));
    unsigned short* Wb  = (unsigned short*)alloc((size_t)4 * DIM * DIM * sizeof(unsigned short));
    unsigned short* Wfb = (unsigned short*)alloc((size_t)NCLS * DIM * sizeof(unsigned short));

    k_pre<<<74, 256, 0, stream>>>(W0, W1, W2, W3, Wf, Wb, Wfb, scale_inv, gcount, Gb);
    k_bucket<<<(N_EDGES_C + 1023) / 1024, 256, 0, stream>>>(A, gcount, ebuk, N_EDGES_C);
    k_csr<<<NBUK, 512, 0, stream>>>(ebuk, gcount, ptr, dinv, esrc);

    const int gemm_grid = (N_NODES_C + 63) / 64;
    const int agg_grid  = N_NODES_C / 4;   // exact: 12500

    // layer 0 (A = fp32 X, converted in-register)
    k_gemm_mfma<true><<<gemm_grid, 256, 0, stream>>>(X, Wb + 0 * DIM * DIM, scale_inv + 0, dinv, Gb, N_NODES_C);
    k_agg<false><<<agg_grid, 256, 0, stream>>>(Gb, b0, dinv, ptr, esrc, nullptr, Hb1);
    // layer 1
    k_gemm_mfma<false><<<gemm_grid, 256, 0, stream>>>(Hb1, Wb + 1 * DIM * DIM, scale_inv + 1, dinv, Gb, N_NODES_C);
    k_agg<true><<<agg_grid, 256, 0, stream>>>(Gb, b1, dinv, ptr, esrc, Hb1, Hb2);
    // layer 2
    k_gemm_mfma<false><<<gemm_grid, 256, 0, stream>>>(Hb2, Wb + 2 * DIM * DIM, scale_inv + 2, dinv, Gb, N_NODES_C);
    k_agg<true><<<agg_grid, 256, 0, stream>>>(Gb, b2, dinv, ptr, esrc, Hb2, Hb1);
    // layer 3
    k_gemm_mfma<false><<<gemm_grid, 256, 0, stream>>>(Hb1, Wb + 3 * DIM * DIM, scale_inv + 3, dinv, Gb, N_NODES_C);
    k_agg<true><<<agg_grid, 256, 0, stream>>>(Gb, b3, dinv, ptr, esrc, Hb1, Hb2);
    // final classifier (MFMA, bf16 Wf)
    k_final<<<(N_NODES_C + 63) / 64, 256, 0, stream>>>(Hb2, Wfb, bf, out, N_NODES_C);
}